// Round 15
// baseline (1077.300 us; speedup 1.0000x reference)
//
#include <hip/hip_runtime.h>
#include <math.h>

#define NND 20000
#define NE  320000
#define NF  128
#define K1P 288            // DIN=262 zero-padded to 288 (9 slabs of 32)
#define EPS 1e-5f
#define TE  64             // edges per tile
#define NT  256
#define NTILES (NE / TE)   // 5000
#define XST 136            // LDS stride for 128-wide bf16 tiles (shorts)
#define BST 40             // LDS stride for B slab rows (shorts)

typedef short short8 __attribute__((ext_vector_type(8)));
typedef float float4v __attribute__((ext_vector_type(4)));

__device__ __forceinline__ float psif(float z) {
    return copysignf(log1pf(fabsf(z)), z);
}
__device__ __forceinline__ float sigm(float z) {
    return 1.f / (1.f + expf(-z));
}
__device__ __forceinline__ short f2bf(float f) {
    union { float f; unsigned u; } v; v.f = f;
    unsigned r = v.u + 0x7fffu + ((v.u >> 16) & 1u);
    return (short)(r >> 16);
}
__device__ __forceinline__ float bf2f(short u) {
    union { unsigned u; float f; } v; v.u = ((unsigned)(unsigned short)u) << 16;
    return v.f;
}
__device__ __forceinline__ float clipf(float v) {
    return fminf(fmaxf(v, -100.f), 100.f);
}

// stage one K=32 slab of Wt [128 rows n][wstride k] (bf16) into LDS bt[128][BST]
__device__ __forceinline__ void stage_b(const unsigned short* __restrict__ wsrc, int wstride,
                                        int ks, short* bt, int t) {
    #pragma unroll
    for (int rr = 0; rr < 2; ++rr) {
        int c = t + rr * 256;          // 512 chunks of 8 bf16
        int n = c >> 2, h = c & 3;
        short8 v = *(const short8*)(wsrc + (size_t)n * wstride + ks * 32 + h * 8);
        *(short8*)(bt + n * BST + h * 8) = v;
    }
}

// B-slab staging split for double-buffered loops (passB)
__device__ __forceinline__ void ldreg_b(const unsigned short* __restrict__ w, int wstride,
                                        int ks, int t, short8* r) {
    #pragma unroll
    for (int rr = 0; rr < 2; ++rr) {
        int c = t + rr * 256;
        int n = c >> 2, h = c & 3;
        r[rr] = *(const short8*)(w + (size_t)n * wstride + ks * 32 + h * 8);
    }
}
__device__ __forceinline__ void wrlds_b(short* bt, int t, const short8* r) {
    #pragma unroll
    for (int rr = 0; rr < 2; ++rr) {
        int c = t + rr * 256;
        int n = c >> 2, h = c & 3;
        *(short8*)(bt + n * BST + h * 8) = r[rr];
    }
}

// ---------------------------------------------------------------------------
// node_gemm: P[n][0:128] = x @ W1top  (bf16 MFMA, fp32 out). 64 rows/block.
// Block 0 also zeroes gstats (runs before passAB0 in stream order).
// ---------------------------------------------------------------------------
__global__ __launch_bounds__(NT, 2)
void node_gemm(const float* __restrict__ x,
               const unsigned short* __restrict__ wt1,   // [128 n][K1P k]
               float* __restrict__ P,
               float* __restrict__ gstats)
{
    __shared__ short lxa[TE * XST];
    __shared__ short lbt[128 * BST];

    const int t = threadIdx.x;
    const int lane = t & 63, quad = lane >> 4, ln15 = lane & 15;
    const int wv = t >> 6, we = wv >> 1, wc = wv & 1;
    const int n0 = blockIdx.x * 64;

    if (blockIdx.x == 0) gstats[t] = 0.f;   // 256 floats, replaces memsetAsync

    {   // stage A tile: fp32 -> bf16 conversion, full 32-short chunk/thread
        int row = t >> 2, q = t & 3;
        int src = min(n0 + row, NND - 1);
        const float4* xp = (const float4*)(x + (size_t)src * NF) + q * 8;
        #pragma unroll
        for (int u = 0; u < 4; ++u) {
            float4 a = xp[2*u], b = xp[2*u+1];
            short8 s;
            s[0]=f2bf(a.x); s[1]=f2bf(a.y); s[2]=f2bf(a.z); s[3]=f2bf(a.w);
            s[4]=f2bf(b.x); s[5]=f2bf(b.y); s[6]=f2bf(b.z); s[7]=f2bf(b.w);
            *(short8*)(lxa + row * XST + q * 32 + u * 8) = s;
        }
    }

    float4v acc[2][4];
    #pragma unroll
    for (int a = 0; a < 2; ++a)
        #pragma unroll
        for (int b = 0; b < 4; ++b) { float4v z = {0.f,0.f,0.f,0.f}; acc[a][b] = z; }

    for (int ks = 0; ks < 4; ++ks) {
        __syncthreads();
        stage_b(wt1, K1P, ks, lbt, t);
        __syncthreads();
        short8 af[2], bfr[4];
        #pragma unroll
        for (int ef = 0; ef < 2; ++ef)
            af[ef] = *(const short8*)(lxa + (we*32 + ef*16 + ln15) * XST + ks*32 + quad*8);
        #pragma unroll
        for (int fc = 0; fc < 4; ++fc)
            bfr[fc] = *(const short8*)(lbt + (wc*64 + fc*16 + ln15) * BST + quad*8);
        #pragma unroll
        for (int ef = 0; ef < 2; ++ef)
            #pragma unroll
            for (int fc = 0; fc < 4; ++fc)
                acc[ef][fc] = __builtin_amdgcn_mfma_f32_16x16x32_bf16(af[ef], bfr[fc], acc[ef][fc], 0, 0, 0);
    }
    #pragma unroll
    for (int fc = 0; fc < 4; ++fc) {
        int c = wc * 64 + fc * 16 + ln15;
        #pragma unroll
        for (int ef = 0; ef < 2; ++ef)
            #pragma unroll
            for (int rg = 0; rg < 4; ++rg) {
                int nrow = n0 + we * 32 + ef * 16 + quad * 4 + rg;
                if (nrow < NND)
                    P[(size_t)nrow * NF + c] = acc[ef][fc][rg];
            }
    }
}

// ---------------------------------------------------------------------------
// passAB0: norms (fp32 x) + edge-GEMM over x_j (4 slabs) + ext (1 slab),
//          SINGLE-buffered B (LDS 31.7 KB -> 4 blocks/CU), x_j prefetched.
//          launch_bounds (256,4): VGPR cap 128, no dbuf staging regs -> fits.
//          Epilogue adds P[row] in fp32 -> stats + hpre bf16.
// ---------------------------------------------------------------------------
__global__ __launch_bounds__(NT, 4)
void passAB0(const float* __restrict__ x,
             const float* __restrict__ P,
             const int* __restrict__ rowS,
             const int* __restrict__ colS,
             const float* __restrict__ eaS,
             const unsigned short* __restrict__ wt1,
             unsigned short* __restrict__ hpre,
             float* __restrict__ gstats)
{
    __shared__ short lxj[TE * XST];     // x_j bf16 A-tile; reused as hpre staging
    __shared__ short lext[TE * 32];
    __shared__ short lbt[128 * BST];    // single B slab buffer

    const int t = threadIdx.x;
    const int lane = t & 63, quad = lane >> 4, ln15 = lane & 15;
    const int wv = t >> 6, we = wv >> 1, wc = wv & 1;
    const int le = t >> 2, q = t & 3;

    float ss[4] = {0.f,0.f,0.f,0.f}, sq[4] = {0.f,0.f,0.f,0.f};

    // prologue: prefetch tile0's indices + x_j quarter row into regs
    int rcur = 0, ccur = 0;
    float4 xjr[8];
    if (blockIdx.x < NTILES) {
        rcur = rowS[blockIdx.x * TE + le];
        ccur = colS[blockIdx.x * TE + le];
        const float4* p = (const float4*)(x + (size_t)ccur * NF) + q * 8;
        #pragma unroll
        for (int u = 0; u < 8; ++u) xjr[u] = p[u];
    }

    for (int tile = blockIdx.x; tile < NTILES; tile += gridDim.x) {
        const int e0 = tile * TE;
        const int tn = tile + gridDim.x;
        int rnxt = rcur, cnxt = ccur;
        if (tn < NTILES) {                       // issue next-tile index loads early
            rnxt = rowS[tn * TE + le];
            cnxt = colS[tn * TE + le];
        }
        float4 xir[8];
        {   // x_i load (sorted edges -> row reuse -> L1/L2-hot)
            const float4* p = (const float4*)(x + (size_t)rcur * NF) + q * 8;
            #pragma unroll
            for (int u = 0; u < 8; ++u) xir[u] = p[u];
        }

        __syncthreads();   // (1) prev tile's copy-out readers of lxj done

        // norms/dots (fp32) + bf16 x_j tile + ext row
        {
            float nrm = 0.f, dot = 0.f, a00 = 0.f, b00 = 0.f;
            #pragma unroll
            for (int u = 0; u < 4; ++u) {
                float4 a0 = xir[2*u], a1 = xir[2*u+1];
                float4 b0 = xjr[2*u], b1 = xjr[2*u+1];
                if (u == 0) { a00 = a0.x; b00 = b0.x; }
                float d;
                d = a0.x-b0.x; nrm -= d*d; dot -= a0.x*b0.x;
                d = a0.y-b0.y; nrm -= d*d; dot -= a0.y*b0.y;
                d = a0.z-b0.z; nrm -= d*d; dot -= a0.z*b0.z;
                d = a0.w-b0.w; nrm -= d*d; dot -= a0.w*b0.w;
                d = a1.x-b1.x; nrm -= d*d; dot -= a1.x*b1.x;
                d = a1.y-b1.y; nrm -= d*d; dot -= a1.y*b1.y;
                d = a1.z-b1.z; nrm -= d*d; dot -= a1.z*b1.z;
                d = a1.w-b1.w; nrm -= d*d; dot -= a1.w*b1.w;
                short8 sb;
                sb[0]=f2bf(b0.x); sb[1]=f2bf(b0.y); sb[2]=f2bf(b0.z); sb[3]=f2bf(b0.w);
                sb[4]=f2bf(b1.x); sb[5]=f2bf(b1.y); sb[6]=f2bf(b1.z); sb[7]=f2bf(b1.w);
                *(short8*)(lxj + le * XST + q * 32 + u * 8) = sb;
            }
            if (q == 0) {  // metric fix: component 0 carries +, not -
                float d0 = a00 - b00;
                nrm += 2.f*d0*d0;
                dot += 2.f*a00*b00;
            }
            nrm += __shfl_xor(nrm, 1); nrm += __shfl_xor(nrm, 2);
            dot += __shfl_xor(dot, 1); dot += __shfl_xor(dot, 2);
            if (q == 0) {
                float4 ea = ((const float4*)eaS)[e0 + le];
                short8 ev;
                ev[0]=f2bf(ea.x); ev[1]=f2bf(ea.y); ev[2]=f2bf(ea.z); ev[3]=f2bf(ea.w);
                ev[4]=f2bf(psif(nrm)); ev[5]=f2bf(psif(dot)); ev[6]=0; ev[7]=0;
                *(short8*)(lext + le * 32) = ev;
            } else {
                short8 ez = {0,0,0,0,0,0,0,0};
                *(short8*)(lext + le * 32 + q * 8) = ez;
            }
        }

        // prefetch next tile's x_j into regs — drains under K-loop + epilogue
        if (tn < NTILES) {
            const float4* p = (const float4*)(x + (size_t)cnxt * NF) + q * 8;
            #pragma unroll
            for (int u = 0; u < 8; ++u) xjr[u] = p[u];
        }
        rcur = rnxt; ccur = cnxt;

        float4v acc[2][4];
        #pragma unroll
        for (int a = 0; a < 2; ++a)
            #pragma unroll
            for (int b = 0; b < 4; ++b) { float4v z = {0.f,0.f,0.f,0.f}; acc[a][b] = z; }

        // K-loop: slabs 4..8 of W1, single-buffered B (2 barriers/slab)
        for (int ks = 0; ks < 5; ++ks) {
            __syncthreads();   // A-writes visible (ks=0) / prev slab reads done
            stage_b(wt1, K1P, ks + 4, lbt, t);
            __syncthreads();
            const short* asrc; int ak, astr;
            if (ks < 4) { asrc = lxj;  ak = ks * 32; astr = XST; }
            else        { asrc = lext; ak = 0;       astr = 32;  }
            short8 af[2], bfr[4];
            #pragma unroll
            for (int ef = 0; ef < 2; ++ef)
                af[ef] = *(const short8*)(asrc + (we*32 + ef*16 + ln15) * astr + ak + quad*8);
            #pragma unroll
            for (int fc = 0; fc < 4; ++fc)
                bfr[fc] = *(const short8*)(lbt + (wc*64 + fc*16 + ln15) * BST + quad*8);
            #pragma unroll
            for (int ef = 0; ef < 2; ++ef)
                #pragma unroll
                for (int fc = 0; fc < 4; ++fc)
                    acc[ef][fc] = __builtin_amdgcn_mfma_f32_16x16x32_bf16(af[ef], bfr[fc], acc[ef][fc], 0, 0, 0);
        }
        __syncthreads();   // all A/B reads done before epilogue overwrites lxj

        // epilogue: h = acc + P[row] (fp32), stats, bf16 -> lxj staging
        #pragma unroll
        for (int ef = 0; ef < 2; ++ef)
            #pragma unroll
            for (int rg = 0; rg < 4; ++rg) {
                int r = we * 32 + ef * 16 + quad * 4 + rg;
                const float* Pr = P + (size_t)rowS[e0 + r] * NF;
                #pragma unroll
                for (int fc = 0; fc < 4; ++fc) {
                    int c = wc * 64 + fc * 16 + ln15;
                    float v = acc[ef][fc][rg] + Pr[c];   // P rows L1-hot (sorted, ~16x reuse)
                    ss[fc] += v;
                    sq[fc] = fmaf(v, v, sq[fc]);
                    lxj[r * XST + c] = f2bf(v);
                }
            }
        __syncthreads();   // staging visible
        {   // coalesced copy-out: 64 rows x 128 shorts
            int row = t >> 2, qq = t & 3;
            short8* dst = (short8*)(hpre + (size_t)(e0 + row) * NF + qq * 32);
            const short* src = lxj + row * XST + qq * 32;
            dst[0] = *(const short8*)(src);
            dst[1] = *(const short8*)(src + 8);
            dst[2] = *(const short8*)(src + 16);
            dst[3] = *(const short8*)(src + 24);
        }
    }

    // stats reduce: lanes sharing ln15 are stride-16 within the wave
    #pragma unroll
    for (int fc = 0; fc < 4; ++fc) {
        ss[fc] += __shfl_xor(ss[fc], 16); ss[fc] += __shfl_xor(ss[fc], 32);
        sq[fc] += __shfl_xor(sq[fc], 16); sq[fc] += __shfl_xor(sq[fc], 32);
    }
    if (lane < 16) {
        #pragma unroll
        for (int fc = 0; fc < 4; ++fc) {
            int c = wc * 64 + fc * 16 + lane;
            atomicAdd(&gstats[c], ss[fc]);
            atomicAdd(&gstats[128 + c], sq[fc]);
        }
    }
}

// ---------------------------------------------------------------------------
// passB: hpre -> BN(from gstats) -> GEMM1 -> gate -> GEMM2 -> s_e
// Single A-tile buffer (mij overwrites hid) -> 4 blocks/CU.
// ---------------------------------------------------------------------------
__global__ __launch_bounds__(NT, 4)
void passB(const unsigned short* __restrict__ hpre,
           const float* __restrict__ gstats,
           const float* __restrict__ gamma,
           const float* __restrict__ beta,
           const unsigned short* __restrict__ wt2,
           const float* __restrict__ b2,
           const unsigned short* __restrict__ wta,
           const float* __restrict__ ba,
           const float* __restrict__ wb,
           const float* __restrict__ wm,
           const float* __restrict__ bm,
           float* __restrict__ sG)
{
    __shared__ short lxi[TE * XST];     // hid, then mij
    __shared__ short lbt0[128 * BST];
    __shared__ short lbt1[128 * BST];
    __shared__ float gpart[2][TE];
    __shared__ float spart[2][TE];
    __shared__ float wgt[TE];
    __shared__ float scs[NF], sfs[NF];

    const int t = threadIdx.x;
    const int lane = t & 63, quad = lane >> 4, ln15 = lane & 15;
    const int wv = t >> 6, we = wv >> 1, wc = wv & 1;
    const int e0 = blockIdx.x * TE;
    const float bmv = bm[0];

    if (t < NF) {   // fused bn_finalize
        float mu  = gstats[t] * (1.f / NE);
        float var = fmaxf(gstats[128 + t] * (1.f / NE) - mu * mu, 0.f);
        float inv = rsqrtf(var + EPS);
        float sc  = gamma[t] * inv;
        scs[t] = sc;
        sfs[t] = beta[t] - mu * sc;
    }
    __syncthreads();

    // load hpre tile, BN+ReLU, store bf16 hid into lxi
    {
        const int le = t >> 2, q = t & 3;
        const unsigned short* hp = hpre + (size_t)(e0 + le) * NF + q * 32;
        #pragma unroll
        for (int h = 0; h < 4; ++h) {
            short8 v = *(const short8*)(hp + h * 8);
            short o[8];
            #pragma unroll
            for (int i = 0; i < 8; ++i) {
                int ch = q * 32 + h * 8 + i;
                float f = fmaxf(fmaf(bf2f(v[i]), scs[ch], sfs[ch]), 0.f);
                o[i] = f2bf(f);
            }
            *(short8*)(lxi + le * XST + q * 32 + h * 8) = *(short8*)o;
        }
    }

    float4v acc[2][4];
    #pragma unroll
    for (int a = 0; a < 2; ++a)
        #pragma unroll
        for (int b = 0; b < 4; ++b) { float4v z = {0.f,0.f,0.f,0.f}; acc[a][b] = z; }

    // ---- GEMM1: mij_raw = relu(hid @ W2 + b2), double-buffered B ----
    {
        short8 pre[2];
        ldreg_b(wt2, NF, 0, t, pre);
        wrlds_b(lbt0, t, pre);
        __syncthreads();   // covers hid writes too
        for (int ks = 0; ks < 4; ++ks) {
            short8 nxt[2];
            if (ks < 3) ldreg_b(wt2, NF, ks + 1, t, nxt);
            const short* cur = (ks & 1) ? lbt1 : lbt0;
            short8 af[2], bfr[4];
            #pragma unroll
            for (int ef = 0; ef < 2; ++ef)
                af[ef] = *(const short8*)(lxi + (we*32 + ef*16 + ln15) * XST + ks*32 + quad*8);
            #pragma unroll
            for (int fc = 0; fc < 4; ++fc)
                bfr[fc] = *(const short8*)(cur + (wc*64 + fc*16 + ln15) * BST + quad*8);
            #pragma unroll
            for (int ef = 0; ef < 2; ++ef)
                #pragma unroll
                for (int fc = 0; fc < 4; ++fc)
                    acc[ef][fc] = __builtin_amdgcn_mfma_f32_16x16x32_bf16(af[ef], bfr[fc], acc[ef][fc], 0, 0, 0);
            if (ks < 3) wrlds_b((ks & 1) ? lbt0 : lbt1, t, nxt);
            __syncthreads();
        }
    }

    // epilogue1: +b2, ReLU -> mij (bf16) back into lxi; gate partials with Wm
    {
        float p[2][4] = {{0.f,0.f,0.f,0.f},{0.f,0.f,0.f,0.f}};
        #pragma unroll
        for (int fc = 0; fc < 4; ++fc) {
            int c = wc * 64 + fc * 16 + ln15;
            float bb = b2[c], wmv = wm[c];
            #pragma unroll
            for (int ef = 0; ef < 2; ++ef)
                #pragma unroll
                for (int rg = 0; rg < 4; ++rg) {
                    int r = we * 32 + ef * 16 + quad * 4 + rg;
                    float v = fmaxf(acc[ef][fc][rg] + bb, 0.f);
                    lxi[r * XST + c] = f2bf(v);   // all GEMM1 lxi reads done (post-ks3 barrier)
                    p[ef][rg] = fmaf(v, wmv, p[ef][rg]);
                }
        }
        #pragma unroll
        for (int ef = 0; ef < 2; ++ef)
            #pragma unroll
            for (int rg = 0; rg < 4; ++rg) {
                p[ef][rg] += __shfl_xor(p[ef][rg], 1);
                p[ef][rg] += __shfl_xor(p[ef][rg], 2);
                p[ef][rg] += __shfl_xor(p[ef][rg], 4);
                p[ef][rg] += __shfl_xor(p[ef][rg], 8);
            }
        if (ln15 == 0) {
            #pragma unroll
            for (int ef = 0; ef < 2; ++ef)
                #pragma unroll
                for (int rg = 0; rg < 4; ++rg)
                    gpart[wc][we * 32 + ef * 16 + quad * 4 + rg] = p[ef][rg];
        }
    }

    // ---- GEMM2: relu(w * (mij @ Wa) + ba) . Wb ----
    #pragma unroll
    for (int a = 0; a < 2; ++a)
        #pragma unroll
        for (int b = 0; b < 4; ++b) { float4v z = {0.f,0.f,0.f,0.f}; acc[a][b] = z; }
    {
        short8 pre[2];
        ldreg_b(wta, NF, 0, t, pre);
        wrlds_b(lbt0, t, pre);      // lbt0 free (last read at GEMM1 ks=2 barrier)
        __syncthreads();            // covers gpart + mij writes + lbt0
        if (t < TE) wgt[t] = sigm(gpart[0][t] + gpart[1][t] + bmv);
        for (int ks = 0; ks < 4; ++ks) {
            short8 nxt[2];
            if (ks < 3) ldreg_b(wta, NF, ks + 1, t, nxt);
            const short* cur = (ks & 1) ? lbt1 : lbt0;
            short8 af[2], bfr[4];
            #pragma unroll
            for (int ef = 0; ef < 2; ++ef)
                af[ef] = *(const short8*)(lxi + (we*32 + ef*16 + ln15) * XST + ks*32 + quad*8);
            #pragma unroll
            for (int fc = 0; fc < 4; ++fc)
                bfr[fc] = *(const short8*)(cur + (wc*64 + fc*16 + ln15) * BST + quad*8);
            #pragma unroll
            for (int ef = 0; ef < 2; ++ef)
                #pragma unroll
                for (int fc = 0; fc < 4; ++fc)
                    acc[ef][fc] = __builtin_amdgcn_mfma_f32_16x16x32_bf16(af[ef], bfr[fc], acc[ef][fc], 0, 0, 0);
            if (ks < 3) wrlds_b((ks & 1) ? lbt0 : lbt1, t, nxt);
            __syncthreads();
        }
    }
    {
        float p[2][4] = {{0.f,0.f,0.f,0.f},{0.f,0.f,0.f,0.f}};
        #pragma unroll
        for (int fc = 0; fc < 4; ++fc) {
            int c = wc * 64 + fc * 16 + ln15;
            float bav = ba[c], wbv = wb[c];
            #pragma unroll
            for (int ef = 0; ef < 2; ++ef)
                #pragma unroll
                for (int rg = 0; rg < 4; ++rg) {
                    int r = we * 32 + ef * 16 + quad * 4 + rg;
                    float v = fmaxf(fmaf(wgt[r], acc[ef][fc][rg], bav), 0.f);
                    p[ef][rg] = fmaf(v, wbv, p[ef][rg]);
                }
        }
        #pragma unroll
        for (int ef = 0; ef < 2; ++ef)
            #pragma unroll
            for (int rg = 0; rg < 4; ++rg) {
                p[ef][rg] += __shfl_xor(p[ef][rg], 1);
                p[ef][rg] += __shfl_xor(p[ef][rg], 2);
                p[ef][rg] += __shfl_xor(p[ef][rg], 4);
                p[ef][rg] += __shfl_xor(p[ef][rg], 8);
            }
        if (ln15 == 0) {
            #pragma unroll
            for (int ef = 0; ef < 2; ++ef)
                #pragma unroll
                for (int rg = 0; rg < 4; ++rg)
                    spart[wc][we * 32 + ef * 16 + quad * 4 + rg] = p[ef][rg];
        }
    }
    __syncthreads();
    if (t < TE) sG[e0 + t] = spart[0][t] + spart[1][t];
}

// ---------------------------------------------------------------------------
// CSR build + edge reorder
// ---------------------------------------------------------------------------
__global__ __launch_bounds__(NT)
void hist_k(const int* __restrict__ ei, int* __restrict__ deg)
{
    int e = blockIdx.x * NT + threadIdx.x;
    if (e < NE) atomicAdd(&deg[ei[e]], 1);
}

__global__ __launch_bounds__(NT)
void scan_k(const int* __restrict__ deg, int* __restrict__ rowstart,
            int* __restrict__ cursor)
{
    __shared__ int part[NT];
    const int t = threadIdx.x;
    const int CH = (NND + NT - 1) / NT;
    const int base = t * CH;
    int sum = 0;
    for (int i = 0; i < CH; ++i) {
        int idx = base + i;
        if (idx < NND) sum += deg[idx];
    }
    part[t] = sum;
    __syncthreads();
    int pre = 0;
    for (int j = 0; j < t; ++j) pre += part[j];
    int run = pre;
    for (int i = 0; i < CH; ++i) {
        int idx = base + i;
        if (idx < NND) {
            rowstart[idx] = run;
            cursor[idx]   = run;
            run += deg[idx];
        }
    }
    if (t == NT - 1) rowstart[NND] = run;
}

__global__ __launch_bounds__(NT)
void fill_k(const int* __restrict__ ei, int* __restrict__ cursor,
            int* __restrict__ perm)
{
    int e = blockIdx.x * NT + threadIdx.x;
    if (e < NE) {
        int pos = atomicAdd(&cursor[ei[e]], 1);
        perm[pos] = e;
    }
}

__global__ __launch_bounds__(NT)
void prep_edges(const int* __restrict__ ei, const float* __restrict__ eattr,
                const int* __restrict__ perm,
                int* __restrict__ rowS, int* __restrict__ colS,
                float* __restrict__ eaS)
{
    int p = blockIdx.x * NT + threadIdx.x;
    if (p >= NE) return;
    int e = perm[p];
    rowS[p] = ei[e];
    colS[p] = ei[NE + e];
    ((float4*)eaS)[p] = ((const float4*)eattr)[e];
}

// ---------------------------------------------------------------------------
// Aggregation: one wave per node; 2-deep software pipeline on x[col] rows.
// ---------------------------------------------------------------------------
__global__ __launch_bounds__(NT)
void aggregate_k(const float* __restrict__ x,
                 const float* __restrict__ sG,
                 const int* __restrict__ rowstart,
                 const int* __restrict__ colS,
                 float* __restrict__ xn)
{
    const int w  = (blockIdx.x * NT + threadIdx.x) >> 6;
    const int ln = threadIdx.x & 63;
    if (w >= NND) return;
    const int beg = rowstart[w], end = rowstart[w + 1];
    const float* xr = x + (size_t)w * NF;
    const float xr0 = xr[ln], xr1 = xr[ln + 64];
    float a0 = 0.f, a1 = 0.f;
    int p = beg;
    if (p < end) {
        int c = colS[p];
        float v0 = x[(size_t)c * NF + ln];
        float v1 = x[(size_t)c * NF + 64 + ln];
        for (; p + 1 < end; ++p) {
            int c2 = colS[p + 1];
            float w0 = x[(size_t)c2 * NF + ln];
            float w1 = x[(size_t)c2 * NF + 64 + ln];
            float s = sG[p];
            a0 += clipf((xr0 - v0) * s);
            a1 += clipf((xr1 - v1) * s);
            v0 = w0; v1 = w1;
        }
        float s = sG[p];
        a0 += clipf((xr0 - v0) * s);
        a1 += clipf((xr1 - v1) * s);
    }
    xn[(size_t)w * NF + ln]      = xr0 + a0;
    xn[(size_t)w * NF + ln + 64] = xr1 + a1;
}

// Last layer: aggregate fused with final Linear+sigmoid
__global__ __launch_bounds__(NT)
void aggregate_final(const float* __restrict__ x,
                     const float* __restrict__ sG,
                     const int* __restrict__ rowstart,
                     const int* __restrict__ colS,
                     const float* __restrict__ We,
                     const float* __restrict__ be,
                     float* __restrict__ out)
{
    const int w  = (blockIdx.x * NT + threadIdx.x) >> 6;
    const int ln = threadIdx.x & 63;
    if (w >= NND) return;
    const int beg = rowstart[w], end = rowstart[w + 1];
    const float* xr = x + (size_t)w * NF;
    const float xr0 = xr[ln], xr1 = xr[ln + 64];
    float a0 = 0.f, a1 = 0.f;
    int p = beg;
    if (p < end) {
        int c = colS[p];
        float v0 = x[(size_t)c * NF + ln];
        float v1 = x[(size_t)c * NF + 64 + ln];
        for (; p + 1 < end; ++p) {
            int c2 = colS[p + 1];
            float w0 = x[(size_t)c2 * NF + ln];
            float w1 = x[(size_t)c2 * NF + 64 + ln];
            float s = sG[p];
            a0 += clipf((xr0 - v0) * s);
            a1 += clipf((xr1 - v1) * s);
            v0 = w0; v1 = w1;
        }
        float s = sG[p];
        a0 += clipf((xr0 - v0) * s);
        a1 += clipf((xr1 - v1) * s);
    }
    const float v0 = xr0 + a0;
    const float v1 = xr1 + a1;
    float o0 = v0 * We[ln * 2]     + v1 * We[(ln + 64) * 2];
    float o1 = v0 * We[ln * 2 + 1] + v1 * We[(ln + 64) * 2 + 1];
    #pragma unroll
    for (int m = 1; m < 64; m <<= 1) { o0 += __shfl_xor(o0, m); o1 += __shfl_xor(o1, m); }
    if (ln == 0) {
        out[w * 2]     = sigm(o0 + be[0]);
        out[w * 2 + 1] = sigm(o1 + be[1]);
    }
}

// ---------------------------------------------------------------------------
// Weight prep
// ---------------------------------------------------------------------------
__global__ __launch_bounds__(NT)
void prep_w1(const float* __restrict__ W1, unsigned short* __restrict__ wt1)
{
    int i = blockIdx.x * NT + threadIdx.x;
    if (i >= 3 * 128 * K1P) return;
    int l = i / (128 * K1P);
    int r = i % (128 * K1P);
    int n = r / K1P, k = r % K1P;
    float v = (k < 262) ? W1[((size_t)l * 262 + k) * 128 + n] : 0.f;
    wt1[i] = (unsigned short)f2bf(v);
}

__global__ __launch_bounds__(NT)
void prep_w128(const float* __restrict__ W, unsigned short* __restrict__ wt)
{
    int i = blockIdx.x * NT + threadIdx.x;
    if (i >= 3 * 128 * 128) return;
    int l = i / (128 * 128);
    int r = i % (128 * 128);
    int n = r / 128, k = r % 128;
    wt[i] = (unsigned short)f2bf(W[((size_t)l * 128 + k) * 128 + n]);
}

// ---------------------------------------------------------------------------
extern "C" void kernel_launch(void* const* d_in, const int* in_sizes, int n_in,
                              void* d_out, int out_size, void* d_ws, size_t ws_size,
                              hipStream_t stream) {
    const float* x   = (const float*)d_in[0];
    const int*   ei  = (const int*)d_in[1];
    const float* ea  = (const float*)d_in[2];
    const float* W1  = (const float*)d_in[3];
    const float* ga  = (const float*)d_in[4];
    const float* bet = (const float*)d_in[5];
    const float* W2  = (const float*)d_in[6];
    const float* b2  = (const float*)d_in[7];
    const float* Wa  = (const float*)d_in[8];
    const float* ba  = (const float*)d_in[9];
    const float* Wb  = (const float*)d_in[10];
    const float* Wm  = (const float*)d_in[11];
    const float* bm  = (const float*)d_in[12];
    const float* We  = (const float*)d_in[13];
    const float* be  = (const float*)d_in[14];
    float* out = (float*)d_out;

    // bump allocator over d_ws, 32B-aligned
    char* base = (char*)d_ws;
    size_t off = 0;
    auto alloc = [&](size_t bytes) -> void* {
        off = (off + 31) & ~(size_t)31;
        void* p = base + off;
        off += bytes;
        return p;
    };
    float* gstats   = (float*)alloc(256 * sizeof(float));
    int*   deg      = (int*)alloc(NND * sizeof(int));
    int*   rowstart = (int*)alloc((NND + 1) * sizeof(int));
    int*   cursor   = (int*)alloc(NND * sizeof(int));
    int*   perm     = (int*)alloc(NE * sizeof(int));
    int*   rowS     = (int*)alloc(NE * sizeof(int));
    int*   colS     = (int*)alloc(NE * sizeof(int));
    float* eaS      = (float*)alloc((size_t)NE * 4 * sizeof(float));
    float* sG       = (float*)alloc(NE * sizeof(float));
    float* xA       = (float*)alloc((size_t)NND * NF * sizeof(float));
    float* xB       = (float*)alloc((size_t)NND * NF * sizeof(float));
    float* P        = (float*)alloc((size_t)NND * NF * sizeof(float));
    unsigned short* wt1  = (unsigned short*)alloc((size_t)3 * 128 * K1P * 2);
    unsigned short* wt2  = (unsigned short*)alloc((size_t)3 * 128 * 128 * 2);
    unsigned short* wta  = (unsigned short*)alloc((size_t)3 * 128 * 128 * 2);
    unsigned short* hpreG= (unsigned short*)alloc((size_t)NE * NF * 2);

    prep_w1  <<<(3 * 128 * K1P + NT - 1) / NT, NT, 0, stream>>>(W1, wt1);
    prep_w128<<<(3 * 128 * 128 + NT - 1) / NT, NT, 0, stream>>>(W2, wt2);
    prep_w128<<<(3 * 128 * 128 + NT - 1) / NT, NT, 0, stream>>>(Wa, wta);

    hipMemsetAsync(deg, 0, NND * sizeof(int), stream);
    hist_k<<<(NE + NT - 1) / NT, NT, 0, stream>>>(ei, deg);
    scan_k<<<1, NT, 0, stream>>>(deg, rowstart, cursor);
    fill_k<<<(NE + NT - 1) / NT, NT, 0, stream>>>(ei, cursor, perm);
    prep_edges<<<(NE + NT - 1) / NT, NT, 0, stream>>>(ei, ea, perm, rowS, colS, eaS);

    const float* xc = x;
    float* buf[2] = { xA, xB };

    for (int l = 0; l < 3; ++l) {
        node_gemm<<<(NND + 63) / 64, NT, 0, stream>>>(xc, wt1 + (size_t)l * 128 * K1P, P, gstats);
        passAB0<<<2500, NT, 0, stream>>>(xc, P, rowS, colS, eaS,
                                         wt1 + (size_t)l * 128 * K1P, hpreG, gstats);
        passB<<<NTILES, NT, 0, stream>>>(hpreG, gstats, ga + l * NF, bet + l * NF,
                                         wt2 + (size_t)l * 128 * 128, b2 + l * NF,
                                         wta + (size_t)l * 128 * 128, ba + l * NF,
                                         Wb + l * NF, Wm + l * NF, bm + l, sG);
        if (l < 2) {
            float* xn = buf[l & 1];
            aggregate_k<<<(NND * 64 + NT - 1) / NT, NT, 0, stream>>>(xc, sG, rowstart,
                                                                     colS, xn);
            xc = xn;
        } else {
            aggregate_final<<<(NND * 64 + NT - 1) / NT, NT, 0, stream>>>(xc, sG, rowstart,
                                                                         colS, We, be, out);
        }
    }
}

// Round 16
// 809.726 us; speedup vs baseline: 1.3304x; 1.3304x over previous
//
#include <hip/hip_runtime.h>
#include <math.h>

#define NND 20000
#define NE  320000
#define NF  128
#define K1P 288            // DIN=262 zero-padded to 288 (9 slabs of 32)
#define EPS 1e-5f
#define TE  64             // edges per tile
#define NT  256
#define NTILES (NE / TE)   // 5000
#define XST 136            // LDS stride for 128-wide bf16 tiles (shorts)
#define BST 40             // LDS stride for B slab rows (shorts)

typedef short short8 __attribute__((ext_vector_type(8)));
typedef float float4v __attribute__((ext_vector_type(4)));

__device__ __forceinline__ float psif(float z) {
    return copysignf(log1pf(fabsf(z)), z);
}
__device__ __forceinline__ float sigm(float z) {
    return 1.f / (1.f + expf(-z));
}
__device__ __forceinline__ short f2bf(float f) {
    union { float f; unsigned u; } v; v.f = f;
    unsigned r = v.u + 0x7fffu + ((v.u >> 16) & 1u);
    return (short)(r >> 16);
}
__device__ __forceinline__ float bf2f(short u) {
    union { unsigned u; float f; } v; v.u = ((unsigned)(unsigned short)u) << 16;
    return v.f;
}
__device__ __forceinline__ float clipf(float v) {
    return fminf(fmaxf(v, -100.f), 100.f);
}

// stage one K=32 slab of Wt [128 rows n][wstride k] (bf16) into LDS bt[128][BST]
__device__ __forceinline__ void stage_b(const unsigned short* __restrict__ wsrc, int wstride,
                                        int ks, short* bt, int t) {
    #pragma unroll
    for (int rr = 0; rr < 2; ++rr) {
        int c = t + rr * 256;          // 512 chunks of 8 bf16
        int n = c >> 2, h = c & 3;
        short8 v = *(const short8*)(wsrc + (size_t)n * wstride + ks * 32 + h * 8);
        *(short8*)(bt + n * BST + h * 8) = v;
    }
}

// B-slab staging split for double-buffered loops (passB)
__device__ __forceinline__ void ldreg_b(const unsigned short* __restrict__ w, int wstride,
                                        int ks, int t, short8* r) {
    #pragma unroll
    for (int rr = 0; rr < 2; ++rr) {
        int c = t + rr * 256;
        int n = c >> 2, h = c & 3;
        r[rr] = *(const short8*)(w + (size_t)n * wstride + ks * 32 + h * 8);
    }
}
__device__ __forceinline__ void wrlds_b(short* bt, int t, const short8* r) {
    #pragma unroll
    for (int rr = 0; rr < 2; ++rr) {
        int c = t + rr * 256;
        int n = c >> 2, h = c & 3;
        *(short8*)(bt + n * BST + h * 8) = r[rr];
    }
}

// ---------------------------------------------------------------------------
// node_gemm: P[n][0:128] = x @ W1top  (bf16 MFMA, fp32 out). 64 rows/block.
// Block 0 also zeroes gstats (runs before passAB0 in stream order).
// ---------------------------------------------------------------------------
__global__ __launch_bounds__(NT, 2)
void node_gemm(const float* __restrict__ x,
               const unsigned short* __restrict__ wt1,   // [128 n][K1P k]
               float* __restrict__ P,
               float* __restrict__ gstats)
{
    __shared__ short lxa[TE * XST];
    __shared__ short lbt[128 * BST];

    const int t = threadIdx.x;
    const int lane = t & 63, quad = lane >> 4, ln15 = lane & 15;
    const int wv = t >> 6, we = wv >> 1, wc = wv & 1;
    const int n0 = blockIdx.x * 64;

    if (blockIdx.x == 0) gstats[t] = 0.f;   // 256 floats, replaces memsetAsync

    {   // stage A tile: fp32 -> bf16 conversion, full 32-short chunk/thread
        int row = t >> 2, q = t & 3;
        int src = min(n0 + row, NND - 1);
        const float4* xp = (const float4*)(x + (size_t)src * NF) + q * 8;
        #pragma unroll
        for (int u = 0; u < 4; ++u) {
            float4 a = xp[2*u], b = xp[2*u+1];
            short8 s;
            s[0]=f2bf(a.x); s[1]=f2bf(a.y); s[2]=f2bf(a.z); s[3]=f2bf(a.w);
            s[4]=f2bf(b.x); s[5]=f2bf(b.y); s[6]=f2bf(b.z); s[7]=f2bf(b.w);
            *(short8*)(lxa + row * XST + q * 32 + u * 8) = s;
        }
    }

    float4v acc[2][4];
    #pragma unroll
    for (int a = 0; a < 2; ++a)
        #pragma unroll
        for (int b = 0; b < 4; ++b) { float4v z = {0.f,0.f,0.f,0.f}; acc[a][b] = z; }

    for (int ks = 0; ks < 4; ++ks) {
        __syncthreads();
        stage_b(wt1, K1P, ks, lbt, t);
        __syncthreads();
        short8 af[2], bfr[4];
        #pragma unroll
        for (int ef = 0; ef < 2; ++ef)
            af[ef] = *(const short8*)(lxa + (we*32 + ef*16 + ln15) * XST + ks*32 + quad*8);
        #pragma unroll
        for (int fc = 0; fc < 4; ++fc)
            bfr[fc] = *(const short8*)(lbt + (wc*64 + fc*16 + ln15) * BST + quad*8);
        #pragma unroll
        for (int ef = 0; ef < 2; ++ef)
            #pragma unroll
            for (int fc = 0; fc < 4; ++fc)
                acc[ef][fc] = __builtin_amdgcn_mfma_f32_16x16x32_bf16(af[ef], bfr[fc], acc[ef][fc], 0, 0, 0);
    }
    #pragma unroll
    for (int fc = 0; fc < 4; ++fc) {
        int c = wc * 64 + fc * 16 + ln15;
        #pragma unroll
        for (int ef = 0; ef < 2; ++ef)
            #pragma unroll
            for (int rg = 0; rg < 4; ++rg) {
                int nrow = n0 + we * 32 + ef * 16 + quad * 4 + rg;
                if (nrow < NND)
                    P[(size_t)nrow * NF + c] = acc[ef][fc][rg];
            }
    }
}

// ---------------------------------------------------------------------------
// passAB0: norms (fp32 x) + edge-GEMM over x_j (4 slabs) + ext (1 slab),
//          SINGLE-buffered B (LDS 31.7 KB) with launch_bounds (256,2):
//          natural VGPR <=128 -> HW can run 4 blocks/CU, no forced spill.
//          x_j register-prefetched one tile ahead (r14-proven).
//          Epilogue adds P[row] in fp32 -> stats + hpre bf16.
// ---------------------------------------------------------------------------
__global__ __launch_bounds__(NT, 2)
void passAB0(const float* __restrict__ x,
             const float* __restrict__ P,
             const int* __restrict__ rowS,
             const int* __restrict__ colS,
             const float* __restrict__ eaS,
             const unsigned short* __restrict__ wt1,
             unsigned short* __restrict__ hpre,
             float* __restrict__ gstats)
{
    __shared__ short lxj[TE * XST];     // x_j bf16 A-tile; reused as hpre staging
    __shared__ short lext[TE * 32];
    __shared__ short lbt[128 * BST];    // single B slab buffer

    const int t = threadIdx.x;
    const int lane = t & 63, quad = lane >> 4, ln15 = lane & 15;
    const int wv = t >> 6, we = wv >> 1, wc = wv & 1;
    const int le = t >> 2, q = t & 3;

    float ss[4] = {0.f,0.f,0.f,0.f}, sq[4] = {0.f,0.f,0.f,0.f};

    // prologue: prefetch tile0's indices + x_j quarter row into regs
    int rcur = 0, ccur = 0;
    float4 xjr[8];
    if (blockIdx.x < NTILES) {
        rcur = rowS[blockIdx.x * TE + le];
        ccur = colS[blockIdx.x * TE + le];
        const float4* p = (const float4*)(x + (size_t)ccur * NF) + q * 8;
        #pragma unroll
        for (int u = 0; u < 8; ++u) xjr[u] = p[u];
    }

    for (int tile = blockIdx.x; tile < NTILES; tile += gridDim.x) {
        const int e0 = tile * TE;
        const int tn = tile + gridDim.x;
        int rnxt = rcur, cnxt = ccur;
        if (tn < NTILES) {                       // issue next-tile index loads early
            rnxt = rowS[tn * TE + le];
            cnxt = colS[tn * TE + le];
        }
        float4 xir[8];
        {   // x_i load (sorted edges -> row reuse -> L1/L2-hot)
            const float4* p = (const float4*)(x + (size_t)rcur * NF) + q * 8;
            #pragma unroll
            for (int u = 0; u < 8; ++u) xir[u] = p[u];
        }

        __syncthreads();   // (1) prev tile's copy-out readers of lxj done

        // norms/dots (fp32) + bf16 x_j tile + ext row
        {
            float nrm = 0.f, dot = 0.f, a00 = 0.f, b00 = 0.f;
            #pragma unroll
            for (int u = 0; u < 4; ++u) {
                float4 a0 = xir[2*u], a1 = xir[2*u+1];
                float4 b0 = xjr[2*u], b1 = xjr[2*u+1];
                if (u == 0) { a00 = a0.x; b00 = b0.x; }
                float d;
                d = a0.x-b0.x; nrm -= d*d; dot -= a0.x*b0.x;
                d = a0.y-b0.y; nrm -= d*d; dot -= a0.y*b0.y;
                d = a0.z-b0.z; nrm -= d*d; dot -= a0.z*b0.z;
                d = a0.w-b0.w; nrm -= d*d; dot -= a0.w*b0.w;
                d = a1.x-b1.x; nrm -= d*d; dot -= a1.x*b1.x;
                d = a1.y-b1.y; nrm -= d*d; dot -= a1.y*b1.y;
                d = a1.z-b1.z; nrm -= d*d; dot -= a1.z*b1.z;
                d = a1.w-b1.w; nrm -= d*d; dot -= a1.w*b1.w;
                short8 sb;
                sb[0]=f2bf(b0.x); sb[1]=f2bf(b0.y); sb[2]=f2bf(b0.z); sb[3]=f2bf(b0.w);
                sb[4]=f2bf(b1.x); sb[5]=f2bf(b1.y); sb[6]=f2bf(b1.z); sb[7]=f2bf(b1.w);
                *(short8*)(lxj + le * XST + q * 32 + u * 8) = sb;
            }
            if (q == 0) {  // metric fix: component 0 carries +, not -
                float d0 = a00 - b00;
                nrm += 2.f*d0*d0;
                dot += 2.f*a00*b00;
            }
            nrm += __shfl_xor(nrm, 1); nrm += __shfl_xor(nrm, 2);
            dot += __shfl_xor(dot, 1); dot += __shfl_xor(dot, 2);
            if (q == 0) {
                float4 ea = ((const float4*)eaS)[e0 + le];
                short8 ev;
                ev[0]=f2bf(ea.x); ev[1]=f2bf(ea.y); ev[2]=f2bf(ea.z); ev[3]=f2bf(ea.w);
                ev[4]=f2bf(psif(nrm)); ev[5]=f2bf(psif(dot)); ev[6]=0; ev[7]=0;
                *(short8*)(lext + le * 32) = ev;
            } else {
                short8 ez = {0,0,0,0,0,0,0,0};
                *(short8*)(lext + le * 32 + q * 8) = ez;
            }
        }

        // prefetch next tile's x_j into regs — drains under K-loop + epilogue
        if (tn < NTILES) {
            const float4* p = (const float4*)(x + (size_t)cnxt * NF) + q * 8;
            #pragma unroll
            for (int u = 0; u < 8; ++u) xjr[u] = p[u];
        }
        rcur = rnxt; ccur = cnxt;

        float4v acc[2][4];
        #pragma unroll
        for (int a = 0; a < 2; ++a)
            #pragma unroll
            for (int b = 0; b < 4; ++b) { float4v z = {0.f,0.f,0.f,0.f}; acc[a][b] = z; }

        // K-loop: slabs 4..8 of W1, single-buffered B (2 barriers/slab)
        for (int ks = 0; ks < 5; ++ks) {
            __syncthreads();   // A-writes visible (ks=0) / prev slab reads done
            stage_b(wt1, K1P, ks + 4, lbt, t);
            __syncthreads();
            const short* asrc; int ak, astr;
            if (ks < 4) { asrc = lxj;  ak = ks * 32; astr = XST; }
            else        { asrc = lext; ak = 0;       astr = 32;  }
            short8 af[2], bfr[4];
            #pragma unroll
            for (int ef = 0; ef < 2; ++ef)
                af[ef] = *(const short8*)(asrc + (we*32 + ef*16 + ln15) * astr + ak + quad*8);
            #pragma unroll
            for (int fc = 0; fc < 4; ++fc)
                bfr[fc] = *(const short8*)(lbt + (wc*64 + fc*16 + ln15) * BST + quad*8);
            #pragma unroll
            for (int ef = 0; ef < 2; ++ef)
                #pragma unroll
                for (int fc = 0; fc < 4; ++fc)
                    acc[ef][fc] = __builtin_amdgcn_mfma_f32_16x16x32_bf16(af[ef], bfr[fc], acc[ef][fc], 0, 0, 0);
        }
        __syncthreads();   // all A/B reads done before epilogue overwrites lxj

        // epilogue: h = acc + P[row] (fp32), stats, bf16 -> lxj staging
        #pragma unroll
        for (int ef = 0; ef < 2; ++ef)
            #pragma unroll
            for (int rg = 0; rg < 4; ++rg) {
                int r = we * 32 + ef * 16 + quad * 4 + rg;
                const float* Pr = P + (size_t)rowS[e0 + r] * NF;
                #pragma unroll
                for (int fc = 0; fc < 4; ++fc) {
                    int c = wc * 64 + fc * 16 + ln15;
                    float v = acc[ef][fc][rg] + Pr[c];   // P rows L1-hot (sorted, ~16x reuse)
                    ss[fc] += v;
                    sq[fc] = fmaf(v, v, sq[fc]);
                    lxj[r * XST + c] = f2bf(v);
                }
            }
        __syncthreads();   // staging visible
        {   // coalesced copy-out: 64 rows x 128 shorts
            int row = t >> 2, qq = t & 3;
            short8* dst = (short8*)(hpre + (size_t)(e0 + row) * NF + qq * 32);
            const short* src = lxj + row * XST + qq * 32;
            dst[0] = *(const short8*)(src);
            dst[1] = *(const short8*)(src + 8);
            dst[2] = *(const short8*)(src + 16);
            dst[3] = *(const short8*)(src + 24);
        }
    }

    // stats reduce: lanes sharing ln15 are stride-16 within the wave
    #pragma unroll
    for (int fc = 0; fc < 4; ++fc) {
        ss[fc] += __shfl_xor(ss[fc], 16); ss[fc] += __shfl_xor(ss[fc], 32);
        sq[fc] += __shfl_xor(sq[fc], 16); sq[fc] += __shfl_xor(sq[fc], 32);
    }
    if (lane < 16) {
        #pragma unroll
        for (int fc = 0; fc < 4; ++fc) {
            int c = wc * 64 + fc * 16 + lane;
            atomicAdd(&gstats[c], ss[fc]);
            atomicAdd(&gstats[128 + c], sq[fc]);
        }
    }
}

// ---------------------------------------------------------------------------
// passB: hpre -> BN(from gstats) -> GEMM1 -> gate -> GEMM2 -> s_e
// Single A-tile buffer (mij overwrites hid) -> 4 blocks/CU.
// ---------------------------------------------------------------------------
__global__ __launch_bounds__(NT, 4)
void passB(const unsigned short* __restrict__ hpre,
           const float* __restrict__ gstats,
           const float* __restrict__ gamma,
           const float* __restrict__ beta,
           const unsigned short* __restrict__ wt2,
           const float* __restrict__ b2,
           const unsigned short* __restrict__ wta,
           const float* __restrict__ ba,
           const float* __restrict__ wb,
           const float* __restrict__ wm,
           const float* __restrict__ bm,
           float* __restrict__ sG)
{
    __shared__ short lxi[TE * XST];     // hid, then mij
    __shared__ short lbt0[128 * BST];
    __shared__ short lbt1[128 * BST];
    __shared__ float gpart[2][TE];
    __shared__ float spart[2][TE];
    __shared__ float wgt[TE];
    __shared__ float scs[NF], sfs[NF];

    const int t = threadIdx.x;
    const int lane = t & 63, quad = lane >> 4, ln15 = lane & 15;
    const int wv = t >> 6, we = wv >> 1, wc = wv & 1;
    const int e0 = blockIdx.x * TE;
    const float bmv = bm[0];

    if (t < NF) {   // fused bn_finalize
        float mu  = gstats[t] * (1.f / NE);
        float var = fmaxf(gstats[128 + t] * (1.f / NE) - mu * mu, 0.f);
        float inv = rsqrtf(var + EPS);
        float sc  = gamma[t] * inv;
        scs[t] = sc;
        sfs[t] = beta[t] - mu * sc;
    }
    __syncthreads();

    // load hpre tile, BN+ReLU, store bf16 hid into lxi
    {
        const int le = t >> 2, q = t & 3;
        const unsigned short* hp = hpre + (size_t)(e0 + le) * NF + q * 32;
        #pragma unroll
        for (int h = 0; h < 4; ++h) {
            short8 v = *(const short8*)(hp + h * 8);
            short o[8];
            #pragma unroll
            for (int i = 0; i < 8; ++i) {
                int ch = q * 32 + h * 8 + i;
                float f = fmaxf(fmaf(bf2f(v[i]), scs[ch], sfs[ch]), 0.f);
                o[i] = f2bf(f);
            }
            *(short8*)(lxi + le * XST + q * 32 + h * 8) = *(short8*)o;
        }
    }

    float4v acc[2][4];
    #pragma unroll
    for (int a = 0; a < 2; ++a)
        #pragma unroll
        for (int b = 0; b < 4; ++b) { float4v z = {0.f,0.f,0.f,0.f}; acc[a][b] = z; }

    // ---- GEMM1: mij_raw = relu(hid @ W2 + b2), double-buffered B ----
    {
        short8 pre[2];
        ldreg_b(wt2, NF, 0, t, pre);
        wrlds_b(lbt0, t, pre);
        __syncthreads();   // covers hid writes too
        for (int ks = 0; ks < 4; ++ks) {
            short8 nxt[2];
            if (ks < 3) ldreg_b(wt2, NF, ks + 1, t, nxt);
            const short* cur = (ks & 1) ? lbt1 : lbt0;
            short8 af[2], bfr[4];
            #pragma unroll
            for (int ef = 0; ef < 2; ++ef)
                af[ef] = *(const short8*)(lxi + (we*32 + ef*16 + ln15) * XST + ks*32 + quad*8);
            #pragma unroll
            for (int fc = 0; fc < 4; ++fc)
                bfr[fc] = *(const short8*)(cur + (wc*64 + fc*16 + ln15) * BST + quad*8);
            #pragma unroll
            for (int ef = 0; ef < 2; ++ef)
                #pragma unroll
                for (int fc = 0; fc < 4; ++fc)
                    acc[ef][fc] = __builtin_amdgcn_mfma_f32_16x16x32_bf16(af[ef], bfr[fc], acc[ef][fc], 0, 0, 0);
            if (ks < 3) wrlds_b((ks & 1) ? lbt0 : lbt1, t, nxt);
            __syncthreads();
        }
    }

    // epilogue1: +b2, ReLU -> mij (bf16) back into lxi; gate partials with Wm
    {
        float p[2][4] = {{0.f,0.f,0.f,0.f},{0.f,0.f,0.f,0.f}};
        #pragma unroll
        for (int fc = 0; fc < 4; ++fc) {
            int c = wc * 64 + fc * 16 + ln15;
            float bb = b2[c], wmv = wm[c];
            #pragma unroll
            for (int ef = 0; ef < 2; ++ef)
                #pragma unroll
                for (int rg = 0; rg < 4; ++rg) {
                    int r = we * 32 + ef * 16 + quad * 4 + rg;
                    float v = fmaxf(acc[ef][fc][rg] + bb, 0.f);
                    lxi[r * XST + c] = f2bf(v);   // all GEMM1 lxi reads done (post-ks3 barrier)
                    p[ef][rg] = fmaf(v, wmv, p[ef][rg]);
                }
        }
        #pragma unroll
        for (int ef = 0; ef < 2; ++ef)
            #pragma unroll
            for (int rg = 0; rg < 4; ++rg) {
                p[ef][rg] += __shfl_xor(p[ef][rg], 1);
                p[ef][rg] += __shfl_xor(p[ef][rg], 2);
                p[ef][rg] += __shfl_xor(p[ef][rg], 4);
                p[ef][rg] += __shfl_xor(p[ef][rg], 8);
            }
        if (ln15 == 0) {
            #pragma unroll
            for (int ef = 0; ef < 2; ++ef)
                #pragma unroll
                for (int rg = 0; rg < 4; ++rg)
                    gpart[wc][we * 32 + ef * 16 + quad * 4 + rg] = p[ef][rg];
        }
    }

    // ---- GEMM2: relu(w * (mij @ Wa) + ba) . Wb ----
    #pragma unroll
    for (int a = 0; a < 2; ++a)
        #pragma unroll
        for (int b = 0; b < 4; ++b) { float4v z = {0.f,0.f,0.f,0.f}; acc[a][b] = z; }
    {
        short8 pre[2];
        ldreg_b(wta, NF, 0, t, pre);
        wrlds_b(lbt0, t, pre);      // lbt0 free (last read at GEMM1 ks=2 barrier)
        __syncthreads();            // covers gpart + mij writes + lbt0
        if (t < TE) wgt[t] = sigm(gpart[0][t] + gpart[1][t] + bmv);
        for (int ks = 0; ks < 4; ++ks) {
            short8 nxt[2];
            if (ks < 3) ldreg_b(wta, NF, ks + 1, t, nxt);
            const short* cur = (ks & 1) ? lbt1 : lbt0;
            short8 af[2], bfr[4];
            #pragma unroll
            for (int ef = 0; ef < 2; ++ef)
                af[ef] = *(const short8*)(lxi + (we*32 + ef*16 + ln15) * XST + ks*32 + quad*8);
            #pragma unroll
            for (int fc = 0; fc < 4; ++fc)
                bfr[fc] = *(const short8*)(cur + (wc*64 + fc*16 + ln15) * BST + quad*8);
            #pragma unroll
            for (int ef = 0; ef < 2; ++ef)
                #pragma unroll
                for (int fc = 0; fc < 4; ++fc)
                    acc[ef][fc] = __builtin_amdgcn_mfma_f32_16x16x32_bf16(af[ef], bfr[fc], acc[ef][fc], 0, 0, 0);
            if (ks < 3) wrlds_b((ks & 1) ? lbt0 : lbt1, t, nxt);
            __syncthreads();
        }
    }
    {
        float p[2][4] = {{0.f,0.f,0.f,0.f},{0.f,0.f,0.f,0.f}};
        #pragma unroll
        for (int fc = 0; fc < 4; ++fc) {
            int c = wc * 64 + fc * 16 + ln15;
            float bav = ba[c], wbv = wb[c];
            #pragma unroll
            for (int ef = 0; ef < 2; ++ef)
                #pragma unroll
                for (int rg = 0; rg < 4; ++rg) {
                    int r = we * 32 + ef * 16 + quad * 4 + rg;
                    float v = fmaxf(fmaf(wgt[r], acc[ef][fc][rg], bav), 0.f);
                    p[ef][rg] = fmaf(v, wbv, p[ef][rg]);
                }
        }
        #pragma unroll
        for (int ef = 0; ef < 2; ++ef)
            #pragma unroll
            for (int rg = 0; rg < 4; ++rg) {
                p[ef][rg] += __shfl_xor(p[ef][rg], 1);
                p[ef][rg] += __shfl_xor(p[ef][rg], 2);
                p[ef][rg] += __shfl_xor(p[ef][rg], 4);
                p[ef][rg] += __shfl_xor(p[ef][rg], 8);
            }
        if (ln15 == 0) {
            #pragma unroll
            for (int ef = 0; ef < 2; ++ef)
                #pragma unroll
                for (int rg = 0; rg < 4; ++rg)
                    spart[wc][we * 32 + ef * 16 + quad * 4 + rg] = p[ef][rg];
        }
    }
    __syncthreads();
    if (t < TE) sG[e0 + t] = spart[0][t] + spart[1][t];
}

// ---------------------------------------------------------------------------
// CSR build + edge reorder
// ---------------------------------------------------------------------------
__global__ __launch_bounds__(NT)
void hist_k(const int* __restrict__ ei, int* __restrict__ deg)
{
    int e = blockIdx.x * NT + threadIdx.x;
    if (e < NE) atomicAdd(&deg[ei[e]], 1);
}

__global__ __launch_bounds__(NT)
void scan_k(const int* __restrict__ deg, int* __restrict__ rowstart,
            int* __restrict__ cursor)
{
    __shared__ int part[NT];
    const int t = threadIdx.x;
    const int CH = (NND + NT - 1) / NT;
    const int base = t * CH;
    int sum = 0;
    for (int i = 0; i < CH; ++i) {
        int idx = base + i;
        if (idx < NND) sum += deg[idx];
    }
    part[t] = sum;
    __syncthreads();
    int pre = 0;
    for (int j = 0; j < t; ++j) pre += part[j];
    int run = pre;
    for (int i = 0; i < CH; ++i) {
        int idx = base + i;
        if (idx < NND) {
            rowstart[idx] = run;
            cursor[idx]   = run;
            run += deg[idx];
        }
    }
    if (t == NT - 1) rowstart[NND] = run;
}

__global__ __launch_bounds__(NT)
void fill_k(const int* __restrict__ ei, int* __restrict__ cursor,
            int* __restrict__ perm)
{
    int e = blockIdx.x * NT + threadIdx.x;
    if (e < NE) {
        int pos = atomicAdd(&cursor[ei[e]], 1);
        perm[pos] = e;
    }
}

__global__ __launch_bounds__(NT)
void prep_edges(const int* __restrict__ ei, const float* __restrict__ eattr,
                const int* __restrict__ perm,
                int* __restrict__ rowS, int* __restrict__ colS,
                float* __restrict__ eaS)
{
    int p = blockIdx.x * NT + threadIdx.x;
    if (p >= NE) return;
    int e = perm[p];
    rowS[p] = ei[e];
    colS[p] = ei[NE + e];
    ((float4*)eaS)[p] = ((const float4*)eattr)[e];
}

// ---------------------------------------------------------------------------
// Aggregation: one wave per node; 2-deep software pipeline on x[col] rows.
// ---------------------------------------------------------------------------
__global__ __launch_bounds__(NT)
void aggregate_k(const float* __restrict__ x,
                 const float* __restrict__ sG,
                 const int* __restrict__ rowstart,
                 const int* __restrict__ colS,
                 float* __restrict__ xn)
{
    const int w  = (blockIdx.x * NT + threadIdx.x) >> 6;
    const int ln = threadIdx.x & 63;
    if (w >= NND) return;
    const int beg = rowstart[w], end = rowstart[w + 1];
    const float* xr = x + (size_t)w * NF;
    const float xr0 = xr[ln], xr1 = xr[ln + 64];
    float a0 = 0.f, a1 = 0.f;
    int p = beg;
    if (p < end) {
        int c = colS[p];
        float v0 = x[(size_t)c * NF + ln];
        float v1 = x[(size_t)c * NF + 64 + ln];
        for (; p + 1 < end; ++p) {
            int c2 = colS[p + 1];
            float w0 = x[(size_t)c2 * NF + ln];
            float w1 = x[(size_t)c2 * NF + 64 + ln];
            float s = sG[p];
            a0 += clipf((xr0 - v0) * s);
            a1 += clipf((xr1 - v1) * s);
            v0 = w0; v1 = w1;
        }
        float s = sG[p];
        a0 += clipf((xr0 - v0) * s);
        a1 += clipf((xr1 - v1) * s);
    }
    xn[(size_t)w * NF + ln]      = xr0 + a0;
    xn[(size_t)w * NF + ln + 64] = xr1 + a1;
}

// Last layer: aggregate fused with final Linear+sigmoid
__global__ __launch_bounds__(NT)
void aggregate_final(const float* __restrict__ x,
                     const float* __restrict__ sG,
                     const int* __restrict__ rowstart,
                     const int* __restrict__ colS,
                     const float* __restrict__ We,
                     const float* __restrict__ be,
                     float* __restrict__ out)
{
    const int w  = (blockIdx.x * NT + threadIdx.x) >> 6;
    const int ln = threadIdx.x & 63;
    if (w >= NND) return;
    const int beg = rowstart[w], end = rowstart[w + 1];
    const float* xr = x + (size_t)w * NF;
    const float xr0 = xr[ln], xr1 = xr[ln + 64];
    float a0 = 0.f, a1 = 0.f;
    int p = beg;
    if (p < end) {
        int c = colS[p];
        float v0 = x[(size_t)c * NF + ln];
        float v1 = x[(size_t)c * NF + 64 + ln];
        for (; p + 1 < end; ++p) {
            int c2 = colS[p + 1];
            float w0 = x[(size_t)c2 * NF + ln];
            float w1 = x[(size_t)c2 * NF + 64 + ln];
            float s = sG[p];
            a0 += clipf((xr0 - v0) * s);
            a1 += clipf((xr1 - v1) * s);
            v0 = w0; v1 = w1;
        }
        float s = sG[p];
        a0 += clipf((xr0 - v0) * s);
        a1 += clipf((xr1 - v1) * s);
    }
    const float v0 = xr0 + a0;
    const float v1 = xr1 + a1;
    float o0 = v0 * We[ln * 2]     + v1 * We[(ln + 64) * 2];
    float o1 = v0 * We[ln * 2 + 1] + v1 * We[(ln + 64) * 2 + 1];
    #pragma unroll
    for (int m = 1; m < 64; m <<= 1) { o0 += __shfl_xor(o0, m); o1 += __shfl_xor(o1, m); }
    if (ln == 0) {
        out[w * 2]     = sigm(o0 + be[0]);
        out[w * 2 + 1] = sigm(o1 + be[1]);
    }
}

// ---------------------------------------------------------------------------
// Weight prep
// ---------------------------------------------------------------------------
__global__ __launch_bounds__(NT)
void prep_w1(const float* __restrict__ W1, unsigned short* __restrict__ wt1)
{
    int i = blockIdx.x * NT + threadIdx.x;
    if (i >= 3 * 128 * K1P) return;
    int l = i / (128 * K1P);
    int r = i % (128 * K1P);
    int n = r / K1P, k = r % K1P;
    float v = (k < 262) ? W1[((size_t)l * 262 + k) * 128 + n] : 0.f;
    wt1[i] = (unsigned short)f2bf(v);
}

__global__ __launch_bounds__(NT)
void prep_w128(const float* __restrict__ W, unsigned short* __restrict__ wt)
{
    int i = blockIdx.x * NT + threadIdx.x;
    if (i >= 3 * 128 * 128) return;
    int l = i / (128 * 128);
    int r = i % (128 * 128);
    int n = r / 128, k = r % 128;
    wt[i] = (unsigned short)f2bf(W[((size_t)l * 128 + k) * 128 + n]);
}

// ---------------------------------------------------------------------------
extern "C" void kernel_launch(void* const* d_in, const int* in_sizes, int n_in,
                              void* d_out, int out_size, void* d_ws, size_t ws_size,
                              hipStream_t stream) {
    const float* x   = (const float*)d_in[0];
    const int*   ei  = (const int*)d_in[1];
    const float* ea  = (const float*)d_in[2];
    const float* W1  = (const float*)d_in[3];
    const float* ga  = (const float*)d_in[4];
    const float* bet = (const float*)d_in[5];
    const float* W2  = (const float*)d_in[6];
    const float* b2  = (const float*)d_in[7];
    const float* Wa  = (const float*)d_in[8];
    const float* ba  = (const float*)d_in[9];
    const float* Wb  = (const float*)d_in[10];
    const float* Wm  = (const float*)d_in[11];
    const float* bm  = (const float*)d_in[12];
    const float* We  = (const float*)d_in[13];
    const float* be  = (const float*)d_in[14];
    float* out = (float*)d_out;

    // bump allocator over d_ws, 32B-aligned
    char* base = (char*)d_ws;
    size_t off = 0;
    auto alloc = [&](size_t bytes) -> void* {
        off = (off + 31) & ~(size_t)31;
        void* p = base + off;
        off += bytes;
        return p;
    };
    float* gstats   = (float*)alloc(256 * sizeof(float));
    int*   deg      = (int*)alloc(NND * sizeof(int));
    int*   rowstart = (int*)alloc((NND + 1) * sizeof(int));
    int*   cursor   = (int*)alloc(NND * sizeof(int));
    int*   perm     = (int*)alloc(NE * sizeof(int));
    int*   rowS     = (int*)alloc(NE * sizeof(int));
    int*   colS     = (int*)alloc(NE * sizeof(int));
    float* eaS      = (float*)alloc((size_t)NE * 4 * sizeof(float));
    float* sG       = (float*)alloc(NE * sizeof(float));
    float* xA       = (float*)alloc((size_t)NND * NF * sizeof(float));
    float* xB       = (float*)alloc((size_t)NND * NF * sizeof(float));
    float* P        = (float*)alloc((size_t)NND * NF * sizeof(float));
    unsigned short* wt1  = (unsigned short*)alloc((size_t)3 * 128 * K1P * 2);
    unsigned short* wt2  = (unsigned short*)alloc((size_t)3 * 128 * 128 * 2);
    unsigned short* wta  = (unsigned short*)alloc((size_t)3 * 128 * 128 * 2);
    unsigned short* hpreG= (unsigned short*)alloc((size_t)NE * NF * 2);

    prep_w1  <<<(3 * 128 * K1P + NT - 1) / NT, NT, 0, stream>>>(W1, wt1);
    prep_w128<<<(3 * 128 * 128 + NT - 1) / NT, NT, 0, stream>>>(W2, wt2);
    prep_w128<<<(3 * 128 * 128 + NT - 1) / NT, NT, 0, stream>>>(Wa, wta);

    hipMemsetAsync(deg, 0, NND * sizeof(int), stream);
    hist_k<<<(NE + NT - 1) / NT, NT, 0, stream>>>(ei, deg);
    scan_k<<<1, NT, 0, stream>>>(deg, rowstart, cursor);
    fill_k<<<(NE + NT - 1) / NT, NT, 0, stream>>>(ei, cursor, perm);
    prep_edges<<<(NE + NT - 1) / NT, NT, 0, stream>>>(ei, ea, perm, rowS, colS, eaS);

    const float* xc = x;
    float* buf[2] = { xA, xB };

    for (int l = 0; l < 3; ++l) {
        node_gemm<<<(NND + 63) / 64, NT, 0, stream>>>(xc, wt1 + (size_t)l * 128 * K1P, P, gstats);
        passAB0<<<1280, NT, 0, stream>>>(xc, P, rowS, colS, eaS,
                                         wt1 + (size_t)l * 128 * K1P, hpreG, gstats);
        passB<<<NTILES, NT, 0, stream>>>(hpreG, gstats, ga + l * NF, bet + l * NF,
                                         wt2 + (size_t)l * 128 * 128, b2 + l * NF,
                                         wta + (size_t)l * 128 * 128, ba + l * NF,
                                         Wb + l * NF, Wm + l * NF, bm + l, sG);
        if (l < 2) {
            float* xn = buf[l & 1];
            aggregate_k<<<(NND * 64 + NT - 1) / NT, NT, 0, stream>>>(xc, sG, rowstart,
                                                                     colS, xn);
            xc = xn;
        } else {
            aggregate_final<<<(NND * 64 + NT - 1) / NT, NT, 0, stream>>>(xc, sG, rowstart,
                                                                         colS, We, be, out);
        }
    }
}

// Round 17
// 790.612 us; speedup vs baseline: 1.3626x; 1.0242x over previous
//
#include <hip/hip_runtime.h>
#include <math.h>

#define NND 20000
#define NE  320000
#define NF  128
#define K1P 288            // DIN=262 zero-padded to 288 (9 slabs of 32)
#define EPS 1e-5f
#define TE  64             // edges per tile
#define NT  256
#define NTILES (NE / TE)   // 5000
#define XST 136            // LDS stride for 128-wide bf16 tiles (shorts)
#define BST 40             // LDS stride for B slab rows (shorts)

typedef short short8 __attribute__((ext_vector_type(8)));
typedef float float4v __attribute__((ext_vector_type(4)));

__device__ __forceinline__ float psif(float z) {
    return copysignf(log1pf(fabsf(z)), z);
}
__device__ __forceinline__ float sigm(float z) {
    return 1.f / (1.f + expf(-z));
}
__device__ __forceinline__ short f2bf(float f) {
    union { float f; unsigned u; } v; v.f = f;
    unsigned r = v.u + 0x7fffu + ((v.u >> 16) & 1u);
    return (short)(r >> 16);
}
__device__ __forceinline__ float bf2f(short u) {
    union { unsigned u; float f; } v; v.u = ((unsigned)(unsigned short)u) << 16;
    return v.f;
}
__device__ __forceinline__ float clipf(float v) {
    return fminf(fmaxf(v, -100.f), 100.f);
}

// stage one K=32 slab of Wt [128 rows n][wstride k] (bf16) into LDS bt[128][BST]
__device__ __forceinline__ void stage_b(const unsigned short* __restrict__ wsrc, int wstride,
                                        int ks, short* bt, int t) {
    #pragma unroll
    for (int rr = 0; rr < 2; ++rr) {
        int c = t + rr * 256;          // 512 chunks of 8 bf16
        int n = c >> 2, h = c & 3;
        short8 v = *(const short8*)(wsrc + (size_t)n * wstride + ks * 32 + h * 8);
        *(short8*)(bt + n * BST + h * 8) = v;
    }
}

// B-slab staging split for double-buffered loops
__device__ __forceinline__ void ldreg_b(const unsigned short* __restrict__ w, int wstride,
                                        int ks, int t, short8* r) {
    #pragma unroll
    for (int rr = 0; rr < 2; ++rr) {
        int c = t + rr * 256;
        int n = c >> 2, h = c & 3;
        r[rr] = *(const short8*)(w + (size_t)n * wstride + ks * 32 + h * 8);
    }
}
__device__ __forceinline__ void wrlds_b(short* bt, int t, const short8* r) {
    #pragma unroll
    for (int rr = 0; rr < 2; ++rr) {
        int c = t + rr * 256;
        int n = c >> 2, h = c & 3;
        *(short8*)(bt + n * BST + h * 8) = r[rr];
    }
}

// ---------------------------------------------------------------------------
// node_gemm: P[n][0:128] = x @ W1top  (bf16 MFMA, fp32 out). 64 rows/block.
// Block 0 also zeroes gstats (runs before passAB0 in stream order).
// ---------------------------------------------------------------------------
__global__ __launch_bounds__(NT, 2)
void node_gemm(const float* __restrict__ x,
               const unsigned short* __restrict__ wt1,   // [128 n][K1P k]
               float* __restrict__ P,
               float* __restrict__ gstats)
{
    __shared__ short lxa[TE * XST];
    __shared__ short lbt[128 * BST];

    const int t = threadIdx.x;
    const int lane = t & 63, quad = lane >> 4, ln15 = lane & 15;
    const int wv = t >> 6, we = wv >> 1, wc = wv & 1;
    const int n0 = blockIdx.x * 64;

    if (blockIdx.x == 0) gstats[t] = 0.f;   // 256 floats, replaces memsetAsync

    {   // stage A tile: fp32 -> bf16 conversion, full 32-short chunk/thread
        int row = t >> 2, q = t & 3;
        int src = min(n0 + row, NND - 1);
        const float4* xp = (const float4*)(x + (size_t)src * NF) + q * 8;
        #pragma unroll
        for (int u = 0; u < 4; ++u) {
            float4 a = xp[2*u], b = xp[2*u+1];
            short8 s;
            s[0]=f2bf(a.x); s[1]=f2bf(a.y); s[2]=f2bf(a.z); s[3]=f2bf(a.w);
            s[4]=f2bf(b.x); s[5]=f2bf(b.y); s[6]=f2bf(b.z); s[7]=f2bf(b.w);
            *(short8*)(lxa + row * XST + q * 32 + u * 8) = s;
        }
    }

    float4v acc[2][4];
    #pragma unroll
    for (int a = 0; a < 2; ++a)
        #pragma unroll
        for (int b = 0; b < 4; ++b) { float4v z = {0.f,0.f,0.f,0.f}; acc[a][b] = z; }

    for (int ks = 0; ks < 4; ++ks) {
        __syncthreads();
        stage_b(wt1, K1P, ks, lbt, t);
        __syncthreads();
        short8 af[2], bfr[4];
        #pragma unroll
        for (int ef = 0; ef < 2; ++ef)
            af[ef] = *(const short8*)(lxa + (we*32 + ef*16 + ln15) * XST + ks*32 + quad*8);
        #pragma unroll
        for (int fc = 0; fc < 4; ++fc)
            bfr[fc] = *(const short8*)(lbt + (wc*64 + fc*16 + ln15) * BST + quad*8);
        #pragma unroll
        for (int ef = 0; ef < 2; ++ef)
            #pragma unroll
            for (int fc = 0; fc < 4; ++fc)
                acc[ef][fc] = __builtin_amdgcn_mfma_f32_16x16x32_bf16(af[ef], bfr[fc], acc[ef][fc], 0, 0, 0);
    }
    #pragma unroll
    for (int fc = 0; fc < 4; ++fc) {
        int c = wc * 64 + fc * 16 + ln15;
        #pragma unroll
        for (int ef = 0; ef < 2; ++ef)
            #pragma unroll
            for (int rg = 0; rg < 4; ++rg) {
                int nrow = n0 + we * 32 + ef * 16 + quad * 4 + rg;
                if (nrow < NND)
                    P[(size_t)nrow * NF + c] = acc[ef][fc][rg];
            }
    }
}

// ---------------------------------------------------------------------------
// passAB0: norms (fp32 x) + edge-GEMM over x_j (4 slabs) + ext (1 slab),
//          dbuf B (r12-proven), x_j register-prefetched one tile ahead.
//          launch_bounds (256,2): VGPR cap 256 -> prefetch does NOT spill.
//          Epilogue adds P[row] in fp32 -> stats + hpre bf16.
// ---------------------------------------------------------------------------
__global__ __launch_bounds__(NT, 2)
void passAB0(const float* __restrict__ x,
             const float* __restrict__ P,
             const int* __restrict__ rowS,
             const int* __restrict__ colS,
             const float* __restrict__ eaS,
             const unsigned short* __restrict__ wt1,
             unsigned short* __restrict__ hpre,
             float* __restrict__ gstats)
{
    __shared__ short lxj[TE * XST];     // x_j bf16 A-tile; reused as hpre staging
    __shared__ short lext[TE * 32];
    __shared__ short lbt0[128 * BST];
    __shared__ short lbt1[128 * BST];

    const int t = threadIdx.x;
    const int lane = t & 63, quad = lane >> 4, ln15 = lane & 15;
    const int wv = t >> 6, we = wv >> 1, wc = wv & 1;
    const int le = t >> 2, q = t & 3;

    float ss[4] = {0.f,0.f,0.f,0.f}, sq[4] = {0.f,0.f,0.f,0.f};

    // prologue: prefetch tile0's indices + x_j quarter row into regs
    int rcur = 0, ccur = 0;
    float4 xjr[8];
    if (blockIdx.x < NTILES) {
        rcur = rowS[blockIdx.x * TE + le];
        ccur = colS[blockIdx.x * TE + le];
        const float4* p = (const float4*)(x + (size_t)ccur * NF) + q * 8;
        #pragma unroll
        for (int u = 0; u < 8; ++u) xjr[u] = p[u];
    }

    for (int tile = blockIdx.x; tile < NTILES; tile += gridDim.x) {
        const int e0 = tile * TE;
        const int tn = tile + gridDim.x;
        int rnxt = rcur, cnxt = ccur;
        if (tn < NTILES) {                       // issue next-tile index loads early
            rnxt = rowS[tn * TE + le];
            cnxt = colS[tn * TE + le];
        }
        float4 xir[8];
        {   // x_i load (sorted edges -> row reuse -> L1/L2-hot)
            const float4* p = (const float4*)(x + (size_t)rcur * NF) + q * 8;
            #pragma unroll
            for (int u = 0; u < 8; ++u) xir[u] = p[u];
        }

        __syncthreads();   // (1) prev tile's copy-out readers of lxj done

        // norms/dots (fp32) + bf16 x_j tile + ext row
        {
            float nrm = 0.f, dot = 0.f, a00 = 0.f, b00 = 0.f;
            #pragma unroll
            for (int u = 0; u < 4; ++u) {
                float4 a0 = xir[2*u], a1 = xir[2*u+1];
                float4 b0 = xjr[2*u], b1 = xjr[2*u+1];
                if (u == 0) { a00 = a0.x; b00 = b0.x; }
                float d;
                d = a0.x-b0.x; nrm -= d*d; dot -= a0.x*b0.x;
                d = a0.y-b0.y; nrm -= d*d; dot -= a0.y*b0.y;
                d = a0.z-b0.z; nrm -= d*d; dot -= a0.z*b0.z;
                d = a0.w-b0.w; nrm -= d*d; dot -= a0.w*b0.w;
                d = a1.x-b1.x; nrm -= d*d; dot -= a1.x*b1.x;
                d = a1.y-b1.y; nrm -= d*d; dot -= a1.y*b1.y;
                d = a1.z-b1.z; nrm -= d*d; dot -= a1.z*b1.z;
                d = a1.w-b1.w; nrm -= d*d; dot -= a1.w*b1.w;
                short8 sb;
                sb[0]=f2bf(b0.x); sb[1]=f2bf(b0.y); sb[2]=f2bf(b0.z); sb[3]=f2bf(b0.w);
                sb[4]=f2bf(b1.x); sb[5]=f2bf(b1.y); sb[6]=f2bf(b1.z); sb[7]=f2bf(b1.w);
                *(short8*)(lxj + le * XST + q * 32 + u * 8) = sb;
            }
            if (q == 0) {  // metric fix: component 0 carries +, not -
                float d0 = a00 - b00;
                nrm += 2.f*d0*d0;
                dot += 2.f*a00*b00;
            }
            nrm += __shfl_xor(nrm, 1); nrm += __shfl_xor(nrm, 2);
            dot += __shfl_xor(dot, 1); dot += __shfl_xor(dot, 2);
            if (q == 0) {
                float4 ea = ((const float4*)eaS)[e0 + le];
                short8 ev;
                ev[0]=f2bf(ea.x); ev[1]=f2bf(ea.y); ev[2]=f2bf(ea.z); ev[3]=f2bf(ea.w);
                ev[4]=f2bf(psif(nrm)); ev[5]=f2bf(psif(dot)); ev[6]=0; ev[7]=0;
                *(short8*)(lext + le * 32) = ev;
            } else {
                short8 ez = {0,0,0,0,0,0,0,0};
                *(short8*)(lext + le * 32 + q * 8) = ez;
            }
        }

        // prefetch next tile's x_j into regs — drains under K-loop + epilogue
        if (tn < NTILES) {
            const float4* p = (const float4*)(x + (size_t)cnxt * NF) + q * 8;
            #pragma unroll
            for (int u = 0; u < 8; ++u) xjr[u] = p[u];
        }
        rcur = rnxt; ccur = cnxt;

        float4v acc[2][4];
        #pragma unroll
        for (int a = 0; a < 2; ++a)
            #pragma unroll
            for (int b = 0; b < 4; ++b) { float4v z = {0.f,0.f,0.f,0.f}; acc[a][b] = z; }

        // K-loop: slabs 4..8 of W1, double-buffered B
        {
            short8 pre[2];
            ldreg_b(wt1, K1P, 4, t, pre);
            wrlds_b(lbt0, t, pre);
            __syncthreads();    // (2) covers gather's lxj/lext writes + lbt0
            for (int ks = 0; ks < 5; ++ks) {
                short8 nxt[2];
                if (ks < 4) ldreg_b(wt1, K1P, ks + 5, t, nxt);
                const short* cur = (ks & 1) ? lbt1 : lbt0;
                const short* asrc; int ak, astr;
                if (ks < 4) { asrc = lxj;  ak = ks * 32; astr = XST; }
                else        { asrc = lext; ak = 0;       astr = 32;  }
                short8 af[2], bfr[4];
                #pragma unroll
                for (int ef = 0; ef < 2; ++ef)
                    af[ef] = *(const short8*)(asrc + (we*32 + ef*16 + ln15) * astr + ak + quad*8);
                #pragma unroll
                for (int fc = 0; fc < 4; ++fc)
                    bfr[fc] = *(const short8*)(cur + (wc*64 + fc*16 + ln15) * BST + quad*8);
                #pragma unroll
                for (int ef = 0; ef < 2; ++ef)
                    #pragma unroll
                    for (int fc = 0; fc < 4; ++fc)
                        acc[ef][fc] = __builtin_amdgcn_mfma_f32_16x16x32_bf16(af[ef], bfr[fc], acc[ef][fc], 0, 0, 0);
                if (ks < 4) wrlds_b((ks & 1) ? lbt0 : lbt1, t, nxt);
                __syncthreads();
            }
        }

        // epilogue: h = acc + P[row] (fp32), stats, bf16 -> lxj staging
        #pragma unroll
        for (int ef = 0; ef < 2; ++ef)
            #pragma unroll
            for (int rg = 0; rg < 4; ++rg) {
                int r = we * 32 + ef * 16 + quad * 4 + rg;
                const float* Pr = P + (size_t)rowS[e0 + r] * NF;
                #pragma unroll
                for (int fc = 0; fc < 4; ++fc) {
                    int c = wc * 64 + fc * 16 + ln15;
                    float v = acc[ef][fc][rg] + Pr[c];   // P rows L1-hot (sorted, ~16x reuse)
                    ss[fc] += v;
                    sq[fc] = fmaf(v, v, sq[fc]);
                    lxj[r * XST + c] = f2bf(v);
                }
            }
        __syncthreads();   // staging visible
        {   // coalesced copy-out: 64 rows x 128 shorts
            int row = t >> 2, qq = t & 3;
            short8* dst = (short8*)(hpre + (size_t)(e0 + row) * NF + qq * 32);
            const short* src = lxj + row * XST + qq * 32;
            dst[0] = *(const short8*)(src);
            dst[1] = *(const short8*)(src + 8);
            dst[2] = *(const short8*)(src + 16);
            dst[3] = *(const short8*)(src + 24);
        }
    }

    // stats reduce: lanes sharing ln15 are stride-16 within the wave
    #pragma unroll
    for (int fc = 0; fc < 4; ++fc) {
        ss[fc] += __shfl_xor(ss[fc], 16); ss[fc] += __shfl_xor(ss[fc], 32);
        sq[fc] += __shfl_xor(sq[fc], 16); sq[fc] += __shfl_xor(sq[fc], 32);
    }
    if (lane < 16) {
        #pragma unroll
        for (int fc = 0; fc < 4; ++fc) {
            int c = wc * 64 + fc * 16 + lane;
            atomicAdd(&gstats[c], ss[fc]);
            atomicAdd(&gstats[128 + c], sq[fc]);
        }
    }
}

// ---------------------------------------------------------------------------
// passB: hpre -> BN(from gstats) -> GEMM1 -> gate -> GEMM2 -> s_e
// Single A-tile buffer (mij overwrites hid) -> 4 blocks/CU.
// ---------------------------------------------------------------------------
__global__ __launch_bounds__(NT, 4)
void passB(const unsigned short* __restrict__ hpre,
           const float* __restrict__ gstats,
           const float* __restrict__ gamma,
           const float* __restrict__ beta,
           const unsigned short* __restrict__ wt2,
           const float* __restrict__ b2,
           const unsigned short* __restrict__ wta,
           const float* __restrict__ ba,
           const float* __restrict__ wb,
           const float* __restrict__ wm,
           const float* __restrict__ bm,
           float* __restrict__ sG)
{
    __shared__ short lxi[TE * XST];     // hid, then mij
    __shared__ short lbt0[128 * BST];
    __shared__ short lbt1[128 * BST];
    __shared__ float gpart[2][TE];
    __shared__ float spart[2][TE];
    __shared__ float wgt[TE];
    __shared__ float scs[NF], sfs[NF];

    const int t = threadIdx.x;
    const int lane = t & 63, quad = lane >> 4, ln15 = lane & 15;
    const int wv = t >> 6, we = wv >> 1, wc = wv & 1;
    const int e0 = blockIdx.x * TE;
    const float bmv = bm[0];

    if (t < NF) {   // fused bn_finalize
        float mu  = gstats[t] * (1.f / NE);
        float var = fmaxf(gstats[128 + t] * (1.f / NE) - mu * mu, 0.f);
        float inv = rsqrtf(var + EPS);
        float sc  = gamma[t] * inv;
        scs[t] = sc;
        sfs[t] = beta[t] - mu * sc;
    }
    __syncthreads();

    // load hpre tile, BN+ReLU, store bf16 hid into lxi
    {
        const int le = t >> 2, q = t & 3;
        const unsigned short* hp = hpre + (size_t)(e0 + le) * NF + q * 32;
        #pragma unroll
        for (int h = 0; h < 4; ++h) {
            short8 v = *(const short8*)(hp + h * 8);
            short o[8];
            #pragma unroll
            for (int i = 0; i < 8; ++i) {
                int ch = q * 32 + h * 8 + i;
                float f = fmaxf(fmaf(bf2f(v[i]), scs[ch], sfs[ch]), 0.f);
                o[i] = f2bf(f);
            }
            *(short8*)(lxi + le * XST + q * 32 + h * 8) = *(short8*)o;
        }
    }

    float4v acc[2][4];
    #pragma unroll
    for (int a = 0; a < 2; ++a)
        #pragma unroll
        for (int b = 0; b < 4; ++b) { float4v z = {0.f,0.f,0.f,0.f}; acc[a][b] = z; }

    // ---- GEMM1: mij_raw = relu(hid @ W2 + b2), double-buffered B ----
    {
        short8 pre[2];
        ldreg_b(wt2, NF, 0, t, pre);
        wrlds_b(lbt0, t, pre);
        __syncthreads();   // covers hid writes too
        for (int ks = 0; ks < 4; ++ks) {
            short8 nxt[2];
            if (ks < 3) ldreg_b(wt2, NF, ks + 1, t, nxt);
            const short* cur = (ks & 1) ? lbt1 : lbt0;
            short8 af[2], bfr[4];
            #pragma unroll
            for (int ef = 0; ef < 2; ++ef)
                af[ef] = *(const short8*)(lxi + (we*32 + ef*16 + ln15) * XST + ks*32 + quad*8);
            #pragma unroll
            for (int fc = 0; fc < 4; ++fc)
                bfr[fc] = *(const short8*)(cur + (wc*64 + fc*16 + ln15) * BST + quad*8);
            #pragma unroll
            for (int ef = 0; ef < 2; ++ef)
                #pragma unroll
                for (int fc = 0; fc < 4; ++fc)
                    acc[ef][fc] = __builtin_amdgcn_mfma_f32_16x16x32_bf16(af[ef], bfr[fc], acc[ef][fc], 0, 0, 0);
            if (ks < 3) wrlds_b((ks & 1) ? lbt0 : lbt1, t, nxt);
            __syncthreads();
        }
    }

    // epilogue1: +b2, ReLU -> mij (bf16) back into lxi; gate partials with Wm
    {
        float p[2][4] = {{0.f,0.f,0.f,0.f},{0.f,0.f,0.f,0.f}};
        #pragma unroll
        for (int fc = 0; fc < 4; ++fc) {
            int c = wc * 64 + fc * 16 + ln15;
            float bb = b2[c], wmv = wm[c];
            #pragma unroll
            for (int ef = 0; ef < 2; ++ef)
                #pragma unroll
                for (int rg = 0; rg < 4; ++rg) {
                    int r = we * 32 + ef * 16 + quad * 4 + rg;
                    float v = fmaxf(acc[ef][fc][rg] + bb, 0.f);
                    lxi[r * XST + c] = f2bf(v);   // all GEMM1 lxi reads done (post-ks3 barrier)
                    p[ef][rg] = fmaf(v, wmv, p[ef][rg]);
                }
        }
        #pragma unroll
        for (int ef = 0; ef < 2; ++ef)
            #pragma unroll
            for (int rg = 0; rg < 4; ++rg) {
                p[ef][rg] += __shfl_xor(p[ef][rg], 1);
                p[ef][rg] += __shfl_xor(p[ef][rg], 2);
                p[ef][rg] += __shfl_xor(p[ef][rg], 4);
                p[ef][rg] += __shfl_xor(p[ef][rg], 8);
            }
        if (ln15 == 0) {
            #pragma unroll
            for (int ef = 0; ef < 2; ++ef)
                #pragma unroll
                for (int rg = 0; rg < 4; ++rg)
                    gpart[wc][we * 32 + ef * 16 + quad * 4 + rg] = p[ef][rg];
        }
    }

    // ---- GEMM2: relu(w * (mij @ Wa) + ba) . Wb ----
    #pragma unroll
    for (int a = 0; a < 2; ++a)
        #pragma unroll
        for (int b = 0; b < 4; ++b) { float4v z = {0.f,0.f,0.f,0.f}; acc[a][b] = z; }
    {
        short8 pre[2];
        ldreg_b(wta, NF, 0, t, pre);
        wrlds_b(lbt0, t, pre);      // lbt0 free (last read at GEMM1 ks=2 barrier)
        __syncthreads();            // covers gpart + mij writes + lbt0
        if (t < TE) wgt[t] = sigm(gpart[0][t] + gpart[1][t] + bmv);
        for (int ks = 0; ks < 4; ++ks) {
            short8 nxt[2];
            if (ks < 3) ldreg_b(wta, NF, ks + 1, t, nxt);
            const short* cur = (ks & 1) ? lbt1 : lbt0;
            short8 af[2], bfr[4];
            #pragma unroll
            for (int ef = 0; ef < 2; ++ef)
                af[ef] = *(const short8*)(lxi + (we*32 + ef*16 + ln15) * XST + ks*32 + quad*8);
            #pragma unroll
            for (int fc = 0; fc < 4; ++fc)
                bfr[fc] = *(const short8*)(cur + (wc*64 + fc*16 + ln15) * BST + quad*8);
            #pragma unroll
            for (int ef = 0; ef < 2; ++ef)
                #pragma unroll
                for (int fc = 0; fc < 4; ++fc)
                    acc[ef][fc] = __builtin_amdgcn_mfma_f32_16x16x32_bf16(af[ef], bfr[fc], acc[ef][fc], 0, 0, 0);
            if (ks < 3) wrlds_b((ks & 1) ? lbt0 : lbt1, t, nxt);
            __syncthreads();
        }
    }
    {
        float p[2][4] = {{0.f,0.f,0.f,0.f},{0.f,0.f,0.f,0.f}};
        #pragma unroll
        for (int fc = 0; fc < 4; ++fc) {
            int c = wc * 64 + fc * 16 + ln15;
            float bav = ba[c], wbv = wb[c];
            #pragma unroll
            for (int ef = 0; ef < 2; ++ef)
                #pragma unroll
                for (int rg = 0; rg < 4; ++rg) {
                    int r = we * 32 + ef * 16 + quad * 4 + rg;
                    float v = fmaxf(fmaf(wgt[r], acc[ef][fc][rg], bav), 0.f);
                    p[ef][rg] = fmaf(v, wbv, p[ef][rg]);
                }
        }
        #pragma unroll
        for (int ef = 0; ef < 2; ++ef)
            #pragma unroll
            for (int rg = 0; rg < 4; ++rg) {
                p[ef][rg] += __shfl_xor(p[ef][rg], 1);
                p[ef][rg] += __shfl_xor(p[ef][rg], 2);
                p[ef][rg] += __shfl_xor(p[ef][rg], 4);
                p[ef][rg] += __shfl_xor(p[ef][rg], 8);
            }
        if (ln15 == 0) {
            #pragma unroll
            for (int ef = 0; ef < 2; ++ef)
                #pragma unroll
                for (int rg = 0; rg < 4; ++rg)
                    spart[wc][we * 32 + ef * 16 + quad * 4 + rg] = p[ef][rg];
        }
    }
    __syncthreads();
    if (t < TE) sG[e0 + t] = spart[0][t] + spart[1][t];
}

// ---------------------------------------------------------------------------
// CSR build + edge reorder
// ---------------------------------------------------------------------------
__global__ __launch_bounds__(NT)
void hist_k(const int* __restrict__ ei, int* __restrict__ deg)
{
    int e = blockIdx.x * NT + threadIdx.x;
    if (e < NE) atomicAdd(&deg[ei[e]], 1);
}

__global__ __launch_bounds__(NT)
void scan_k(const int* __restrict__ deg, int* __restrict__ rowstart,
            int* __restrict__ cursor)
{
    __shared__ int part[NT];
    const int t = threadIdx.x;
    const int CH = (NND + NT - 1) / NT;
    const int base = t * CH;
    int sum = 0;
    for (int i = 0; i < CH; ++i) {
        int idx = base + i;
        if (idx < NND) sum += deg[idx];
    }
    part[t] = sum;
    __syncthreads();
    int pre = 0;
    for (int j = 0; j < t; ++j) pre += part[j];
    int run = pre;
    for (int i = 0; i < CH; ++i) {
        int idx = base + i;
        if (idx < NND) {
            rowstart[idx] = run;
            cursor[idx]   = run;
            run += deg[idx];
        }
    }
    if (t == NT - 1) rowstart[NND] = run;
}

__global__ __launch_bounds__(NT)
void fill_k(const int* __restrict__ ei, int* __restrict__ cursor,
            int* __restrict__ perm)
{
    int e = blockIdx.x * NT + threadIdx.x;
    if (e < NE) {
        int pos = atomicAdd(&cursor[ei[e]], 1);
        perm[pos] = e;
    }
}

__global__ __launch_bounds__(NT)
void prep_edges(const int* __restrict__ ei, const float* __restrict__ eattr,
                const int* __restrict__ perm,
                int* __restrict__ rowS, int* __restrict__ colS,
                float* __restrict__ eaS)
{
    int p = blockIdx.x * NT + threadIdx.x;
    if (p >= NE) return;
    int e = perm[p];
    rowS[p] = ei[e];
    colS[p] = ei[NE + e];
    ((float4*)eaS)[p] = ((const float4*)eattr)[e];
}

// ---------------------------------------------------------------------------
// Aggregation: one wave per node; 2-deep software pipeline on x[col] rows.
// ---------------------------------------------------------------------------
__global__ __launch_bounds__(NT)
void aggregate_k(const float* __restrict__ x,
                 const float* __restrict__ sG,
                 const int* __restrict__ rowstart,
                 const int* __restrict__ colS,
                 float* __restrict__ xn)
{
    const int w  = (blockIdx.x * NT + threadIdx.x) >> 6;
    const int ln = threadIdx.x & 63;
    if (w >= NND) return;
    const int beg = rowstart[w], end = rowstart[w + 1];
    const float* xr = x + (size_t)w * NF;
    const float xr0 = xr[ln], xr1 = xr[ln + 64];
    float a0 = 0.f, a1 = 0.f;
    int p = beg;
    if (p < end) {
        int c = colS[p];
        float v0 = x[(size_t)c * NF + ln];
        float v1 = x[(size_t)c * NF + 64 + ln];
        for (; p + 1 < end; ++p) {
            int c2 = colS[p + 1];
            float w0 = x[(size_t)c2 * NF + ln];
            float w1 = x[(size_t)c2 * NF + 64 + ln];
            float s = sG[p];
            a0 += clipf((xr0 - v0) * s);
            a1 += clipf((xr1 - v1) * s);
            v0 = w0; v1 = w1;
        }
        float s = sG[p];
        a0 += clipf((xr0 - v0) * s);
        a1 += clipf((xr1 - v1) * s);
    }
    xn[(size_t)w * NF + ln]      = xr0 + a0;
    xn[(size_t)w * NF + ln + 64] = xr1 + a1;
}

// Last layer: aggregate fused with final Linear+sigmoid
__global__ __launch_bounds__(NT)
void aggregate_final(const float* __restrict__ x,
                     const float* __restrict__ sG,
                     const int* __restrict__ rowstart,
                     const int* __restrict__ colS,
                     const float* __restrict__ We,
                     const float* __restrict__ be,
                     float* __restrict__ out)
{
    const int w  = (blockIdx.x * NT + threadIdx.x) >> 6;
    const int ln = threadIdx.x & 63;
    if (w >= NND) return;
    const int beg = rowstart[w], end = rowstart[w + 1];
    const float* xr = x + (size_t)w * NF;
    const float xr0 = xr[ln], xr1 = xr[ln + 64];
    float a0 = 0.f, a1 = 0.f;
    int p = beg;
    if (p < end) {
        int c = colS[p];
        float v0 = x[(size_t)c * NF + ln];
        float v1 = x[(size_t)c * NF + 64 + ln];
        for (; p + 1 < end; ++p) {
            int c2 = colS[p + 1];
            float w0 = x[(size_t)c2 * NF + ln];
            float w1 = x[(size_t)c2 * NF + 64 + ln];
            float s = sG[p];
            a0 += clipf((xr0 - v0) * s);
            a1 += clipf((xr1 - v1) * s);
            v0 = w0; v1 = w1;
        }
        float s = sG[p];
        a0 += clipf((xr0 - v0) * s);
        a1 += clipf((xr1 - v1) * s);
    }
    const float v0 = xr0 + a0;
    const float v1 = xr1 + a1;
    float o0 = v0 * We[ln * 2]     + v1 * We[(ln + 64) * 2];
    float o1 = v0 * We[ln * 2 + 1] + v1 * We[(ln + 64) * 2 + 1];
    #pragma unroll
    for (int m = 1; m < 64; m <<= 1) { o0 += __shfl_xor(o0, m); o1 += __shfl_xor(o1, m); }
    if (ln == 0) {
        out[w * 2]     = sigm(o0 + be[0]);
        out[w * 2 + 1] = sigm(o1 + be[1]);
    }
}

// ---------------------------------------------------------------------------
// Weight prep
// ---------------------------------------------------------------------------
__global__ __launch_bounds__(NT)
void prep_w1(const float* __restrict__ W1, unsigned short* __restrict__ wt1)
{
    int i = blockIdx.x * NT + threadIdx.x;
    if (i >= 3 * 128 * K1P) return;
    int l = i / (128 * K1P);
    int r = i % (128 * K1P);
    int n = r / K1P, k = r % K1P;
    float v = (k < 262) ? W1[((size_t)l * 262 + k) * 128 + n] : 0.f;
    wt1[i] = (unsigned short)f2bf(v);
}

__global__ __launch_bounds__(NT)
void prep_w128(const float* __restrict__ W, unsigned short* __restrict__ wt)
{
    int i = blockIdx.x * NT + threadIdx.x;
    if (i >= 3 * 128 * 128) return;
    int l = i / (128 * 128);
    int r = i % (128 * 128);
    int n = r / 128, k = r % 128;
    wt[i] = (unsigned short)f2bf(W[((size_t)l * 128 + k) * 128 + n]);
}

// ---------------------------------------------------------------------------
extern "C" void kernel_launch(void* const* d_in, const int* in_sizes, int n_in,
                              void* d_out, int out_size, void* d_ws, size_t ws_size,
                              hipStream_t stream) {
    const float* x   = (const float*)d_in[0];
    const int*   ei  = (const int*)d_in[1];
    const float* ea  = (const float*)d_in[2];
    const float* W1  = (const float*)d_in[3];
    const float* ga  = (const float*)d_in[4];
    const float* bet = (const float*)d_in[5];
    const float* W2  = (const float*)d_in[6];
    const float* b2  = (const float*)d_in[7];
    const float* Wa  = (const float*)d_in[8];
    const float* ba  = (const float*)d_in[9];
    const float* Wb  = (const float*)d_in[10];
    const float* Wm  = (const float*)d_in[11];
    const float* bm  = (const float*)d_in[12];
    const float* We  = (const float*)d_in[13];
    const float* be  = (const float*)d_in[14];
    float* out = (float*)d_out;

    // bump allocator over d_ws, 32B-aligned
    char* base = (char*)d_ws;
    size_t off = 0;
    auto alloc = [&](size_t bytes) -> void* {
        off = (off + 31) & ~(size_t)31;
        void* p = base + off;
        off += bytes;
        return p;
    };
    float* gstats   = (float*)alloc(256 * sizeof(float));
    int*   deg      = (int*)alloc(NND * sizeof(int));
    int*   rowstart = (int*)alloc((NND + 1) * sizeof(int));
    int*   cursor   = (int*)alloc(NND * sizeof(int));
    int*   perm     = (int*)alloc(NE * sizeof(int));
    int*   rowS     = (int*)alloc(NE * sizeof(int));
    int*   colS     = (int*)alloc(NE * sizeof(int));
    float* eaS      = (float*)alloc((size_t)NE * 4 * sizeof(float));
    float* sG       = (float*)alloc(NE * sizeof(float));
    float* xA       = (float*)alloc((size_t)NND * NF * sizeof(float));
    float* xB       = (float*)alloc((size_t)NND * NF * sizeof(float));
    float* P        = (float*)alloc((size_t)NND * NF * sizeof(float));
    unsigned short* wt1  = (unsigned short*)alloc((size_t)3 * 128 * K1P * 2);
    unsigned short* wt2  = (unsigned short*)alloc((size_t)3 * 128 * 128 * 2);
    unsigned short* wta  = (unsigned short*)alloc((size_t)3 * 128 * 128 * 2);
    unsigned short* hpreG= (unsigned short*)alloc((size_t)NE * NF * 2);

    prep_w1  <<<(3 * 128 * K1P + NT - 1) / NT, NT, 0, stream>>>(W1, wt1);
    prep_w128<<<(3 * 128 * 128 + NT - 1) / NT, NT, 0, stream>>>(W2, wt2);
    prep_w128<<<(3 * 128 * 128 + NT - 1) / NT, NT, 0, stream>>>(Wa, wta);

    hipMemsetAsync(deg, 0, NND * sizeof(int), stream);
    hist_k<<<(NE + NT - 1) / NT, NT, 0, stream>>>(ei, deg);
    scan_k<<<1, NT, 0, stream>>>(deg, rowstart, cursor);
    fill_k<<<(NE + NT - 1) / NT, NT, 0, stream>>>(ei, cursor, perm);
    prep_edges<<<(NE + NT - 1) / NT, NT, 0, stream>>>(ei, ea, perm, rowS, colS, eaS);

    const float* xc = x;
    float* buf[2] = { xA, xB };

    for (int l = 0; l < 3; ++l) {
        node_gemm<<<(NND + 63) / 64, NT, 0, stream>>>(xc, wt1 + (size_t)l * 128 * K1P, P, gstats);
        passAB0<<<1280, NT, 0, stream>>>(xc, P, rowS, colS, eaS,
                                         wt1 + (size_t)l * 128 * K1P, hpreG, gstats);
        passB<<<NTILES, NT, 0, stream>>>(hpreG, gstats, ga + l * NF, bet + l * NF,
                                         wt2 + (size_t)l * 128 * 128, b2 + l * NF,
                                         wta + (size_t)l * 128 * 128, ba + l * NF,
                                         Wb + l * NF, Wm + l * NF, bm + l, sG);
        if (l < 2) {
            float* xn = buf[l & 1];
            aggregate_k<<<(NND * 64 + NT - 1) / NT, NT, 0, stream>>>(xc, sG, rowstart,
                                                                     colS, xn);
            xc = xn;
        } else {
            aggregate_final<<<(NND * 64 + NT - 1) / NT, NT, 0, stream>>>(xc, sG, rowstart,
                                                                         colS, We, be, out);
        }
    }
}